// Round 3
// baseline (3201.168 us; speedup 1.0000x reference)
//
#include <hip/hip_runtime.h>

#define N_BOX   43008
#define NT      512
#define SLOTS   84
#define MAXDET  512
#define BATCH   128
#define CAP     1024
#define NBIN    1024
#define NMS_THR 0.4f

static_assert(NT * SLOTS == N_BOX, "slot mismatch");

// ---------- exact-arithmetic helpers (match numpy f32, no FMA contraction) ----------
__device__ __forceinline__ float area_of(float x1, float y1, float x2, float y2) {
    return __fmul_rn(__fsub_rn(x2, x1), __fsub_rn(y2, y1));
}

// a = selected/kept box (areas[i] in reference), b = candidate
__device__ __forceinline__ bool iou_gt_thr(float ax1, float ay1, float ax2, float ay2, float aar,
                                           float bx1, float by1, float bx2, float by2, float bar) {
    float xx1 = fmaxf(ax1, bx1);
    float yy1 = fmaxf(ay1, by1);
    float xx2 = fminf(ax2, bx2);
    float yy2 = fminf(ay2, by2);
    float dx = __fsub_rn(xx2, xx1);
    float dy = __fsub_rn(yy2, yy1);
    if (dx <= 0.0f || dy <= 0.0f) return false;   // inter == 0 -> iou == 0, not > 0.4
    float inter = __fmul_rn(dx, dy);
    float denom = __fsub_rn(__fadd_rn(aar, bar), inter);  // areas[i] + areas[j] - inter
    float iou = inter / denom;                    // IEEE f32 division (no fast-math)
    return iou > NMS_THR;
}

__device__ __forceinline__ int tile_of(float x1, float y1, float x2, float y2) {
    int tx = (int)((x1 + x2) * 0.015625f);  // center/32  (centers < 1024)
    int ty = (int)((y1 + y2) * 0.015625f);
    tx = tx < 0 ? 0 : (tx > 31 ? 31 : tx);
    ty = ty < 0 ? 0 : (ty > 31 ? 31 : ty);
    return ty * 32 + tx;
}

// ---------- init: spatial counting-sort of indices into 32x32 tiles ----------
__global__ void tile_hist_k(const float4* __restrict__ loc4, unsigned int* __restrict__ cnt) {
    int i = blockIdx.x * blockDim.x + threadIdx.x;
    if (i < N_BOX) {
        float4 b = loc4[i];
        atomicAdd(&cnt[tile_of(b.x, b.y, b.z, b.w)], 1u);
    }
}

__global__ __launch_bounds__(1024) void tile_scan_k(const unsigned int* __restrict__ cnt,
                                                    unsigned int* __restrict__ cur) {
    __shared__ unsigned int a[1024];
    int t = threadIdx.x;
    a[t] = cnt[t];
    __syncthreads();
    for (int d = 1; d < 1024; d <<= 1) {
        unsigned v = (t >= d) ? a[t - d] : 0u;
        __syncthreads();
        a[t] += v;
        __syncthreads();
    }
    cur[t] = (t == 0) ? 0u : a[t - 1];   // exclusive offsets (used as scatter cursors)
}

__global__ void tile_scatter_k(const float4* __restrict__ loc4, unsigned int* __restrict__ cur,
                               int* __restrict__ orig_r) {
    int i = blockIdx.x * blockDim.x + threadIdx.x;
    if (i < N_BOX) {
        float4 b = loc4[i];
        unsigned p = atomicAdd(&cur[tile_of(b.x, b.y, b.z, b.w)], 1u);
        orig_r[p] = i;
    }
}

// ---------- main sequential NMS (single workgroup) ----------
__global__ __launch_bounds__(NT) void nms_main_k(const float* __restrict__ loc,
                                                 const float* __restrict__ conf,
                                                 const float* __restrict__ landms,
                                                 const int* __restrict__ orig_r,
                                                 float* __restrict__ out) {
    const float4* loc4 = (const float4*)loc;

    __shared__ unsigned int hist[NBIN];
    __shared__ unsigned int suf[NBIN];
    __shared__ float colS[CAP];
    __shared__ int   colO[CAP];
    __shared__ int   colR[CAP];
    __shared__ int   sortO[BATCH];
    __shared__ int   sortR[BATCH];
    __shared__ float bbx1[BATCH], bby1[BATCH], bbx2[BATCH], bby2[BATCH], bbar[BATCH];
    __shared__ unsigned int mat[BATCH * 4];
    __shared__ int keptOrig[MAXDET];
    __shared__ int keptB[BATCH];
    __shared__ int ctrl[8]; // 0=colCnt 1=bstar 2=M 3=fallback 4=nNew 5=procEnd 6=keptTotal

    const int tid  = threadIdx.x;
    const int base = tid * SLOTS;

    // per-thread candidate scores (registers) + live bitmask + tile bbox
    float s[SLOTS];
    unsigned long long m0 = ~0ull;                       // slots 0..63
    unsigned long long m1 = (1ull << (SLOTS - 64)) - 1;  // slots 64..83
    float tx1 = 1e30f, ty1 = 1e30f, tx2 = -1e30f, ty2 = -1e30f;

    #pragma unroll
    for (int c = 0; c < SLOTS; ++c) {
        int o = orig_r[base + c];
        s[c] = conf[2 * o + 1];
        float4 b = loc4[o];
        tx1 = fminf(tx1, b.x); ty1 = fminf(ty1, b.y);
        tx2 = fmaxf(tx2, b.z); ty2 = fmaxf(ty2, b.w);
    }
    if (tid == 0) ctrl[6] = 0;
    __syncthreads();

    for (int round = 0; round < 600; ++round) {
        // ---- histogram of live scores ----
        for (int b = tid; b < NBIN; b += NT) hist[b] = 0u;
        __syncthreads();
        #pragma unroll
        for (int c = 0; c < SLOTS; ++c) {
            bool live = (c < 64) ? ((m0 >> c) & 1ull) : ((m1 >> (c - 64)) & 1ull);
            if (live) {
                int b = (int)(s[c] * 1024.0f);
                b = b < 0 ? 0 : (b > 1023 ? 1023 : b);
                atomicAdd(&hist[b], 1u);
            }
        }
        __syncthreads();
        // ---- suffix scan (count of live with bin >= b) ----
        for (int b = tid; b < NBIN; b += NT) suf[b] = hist[b];
        __syncthreads();
        for (int d = 1; d < NBIN; d <<= 1) {
            unsigned t0 = (tid + d < NBIN) ? suf[tid + d] : 0u;
            unsigned t1 = (tid + NT + d < NBIN) ? suf[tid + NT + d] : 0u;
            __syncthreads();
            suf[tid] += t0;
            suf[tid + NT] += t1;
            __syncthreads();
        }
        if (suf[0] == 0u) break;    // no live candidates left (uniform)

        // ---- threshold bin: smallest top-bin set with >= BATCH live ----
        for (int b = tid; b < NBIN; b += NT)
            if (suf[b] >= BATCH && (b == NBIN - 1 || suf[b + 1] < BATCH)) ctrl[1] = b;
        if (tid == 0 && suf[0] < BATCH) ctrl[1] = 0;
        __syncthreads();
        if (tid == 0) {
            int bs = ctrl[1];
            int M  = (int)suf[bs];
            int fb = 0;
            if (M > CAP) {
                if (bs + 1 < NBIN && suf[bs + 1] > 0u) { bs = bs + 1; M = (int)suf[bs]; }
                else fb = 1;  // one giant tie-bin: fall back to single argmax
            }
            ctrl[1] = bs; ctrl[2] = M; ctrl[3] = fb; ctrl[0] = 0;
        }
        __syncthreads();
        int bstar = ctrl[1];
        int M     = ctrl[2];
        int fb    = ctrl[3];

        if (fb) {
            // ---- fallback: extract global argmax (score desc, orig asc) ----
            float bs_ = -1.0f; int bo_ = 0x7fffffff; int br_ = 0;
            #pragma unroll
            for (int c = 0; c < SLOTS; ++c) {
                bool live = (c < 64) ? ((m0 >> c) & 1ull) : ((m1 >> (c - 64)) & 1ull);
                if (live) {
                    int o = orig_r[base + c];
                    if (s[c] > bs_ || (s[c] == bs_ && o < bo_)) { bs_ = s[c]; bo_ = o; br_ = base + c; }
                }
            }
            colS[tid] = bs_; colO[tid] = bo_; colR[tid] = br_;
            __syncthreads();
            for (int d = NT / 2; d > 0; d >>= 1) {
                if (tid < d) {
                    if (colS[tid + d] > colS[tid] ||
                        (colS[tid + d] == colS[tid] && colO[tid + d] < colO[tid])) {
                        colS[tid] = colS[tid + d]; colO[tid] = colO[tid + d]; colR[tid] = colR[tid + d];
                    }
                }
                __syncthreads();
            }
            M = 1;
        } else {
            // ---- collect all live with bin >= bstar ----
            #pragma unroll
            for (int c = 0; c < SLOTS; ++c) {
                bool live = (c < 64) ? ((m0 >> c) & 1ull) : ((m1 >> (c - 64)) & 1ull);
                if (live) {
                    int b = (int)(s[c] * 1024.0f);
                    b = b < 0 ? 0 : (b > 1023 ? 1023 : b);
                    if (b >= bstar) {
                        int k = atomicAdd(&ctrl[0], 1);
                        colS[k] = s[c]; colR[k] = base + c; colO[k] = orig_r[base + c];
                    }
                }
            }
            __syncthreads();
            M = ctrl[0];
        }

        // ---- exact rank-sort of collected (score desc, orig-idx asc) ----
        for (int e = tid; e < M; e += NT) {
            float se = colS[e]; int oe = colO[e];
            int rank = 0;
            for (int f = 0; f < M; ++f) {
                float sf = colS[f]; int of = colO[f];
                rank += (sf > se) || (sf == se && of < oe);
            }
            if (rank < BATCH) { sortO[rank] = colO[e]; sortR[rank] = colR[e]; }
        }
        __syncthreads();
        int B = M < BATCH ? M : BATCH;

        // ---- batch boxes into LDS; zero suppression matrix ----
        if (tid < B) {
            float4 b = loc4[sortO[tid]];
            bbx1[tid] = b.x; bby1[tid] = b.y; bbx2[tid] = b.z; bby2[tid] = b.w;
            bbar[tid] = area_of(b.x, b.y, b.z, b.w);
        }
        if (tid < BATCH * 4) mat[tid] = 0u;
        __syncthreads();

        // ---- pairwise suppression matrix: row i bit j (i<j) ----
        for (int p = tid; p < BATCH * BATCH; p += NT) {
            int i = p >> 7, j = p & 127;
            if (i < j && j < B) {
                if (iou_gt_thr(bbx1[i], bby1[i], bbx2[i], bby2[i], bbar[i],
                               bbx1[j], bby1[j], bbx2[j], bby2[j], bbar[j]))
                    atomicOr(&mat[(i << 2) + (j >> 5)], 1u << (j & 31));
            }
        }
        __syncthreads();

        // ---- serial greedy scan over the batch (honors 512-kept cap) ----
        if (tid == 0) {
            unsigned sm0 = 0, sm1 = 0, sm2 = 0, sm3 = 0;
            int kt = ctrl[6], nn = 0, pe = 0;
            for (int i = 0; i < B; ++i) {
                if (kt >= MAXDET) break;
                pe = i + 1;
                unsigned bit = (i < 32 ? (sm0 >> i) : i < 64 ? (sm1 >> (i - 32))
                               : i < 96 ? (sm2 >> (i - 64)) : (sm3 >> (i - 96))) & 1u;
                if (!bit) {
                    keptOrig[kt] = sortO[i]; keptB[nn] = i; ++nn; ++kt;
                    sm0 |= mat[(i << 2) + 0]; sm1 |= mat[(i << 2) + 1];
                    sm2 |= mat[(i << 2) + 2]; sm3 |= mat[(i << 2) + 3];
                }
            }
            ctrl[6] = kt; ctrl[4] = nn; ctrl[5] = pe;
        }
        __syncthreads();
        int nNew = ctrl[4], procEnd = ctrl[5], keptTotal = ctrl[6];

        // ---- mark processed batch members dead (kept and intra-batch-suppressed) ----
        for (int k = 0; k < procEnd; ++k) {
            unsigned sl = (unsigned)(sortR[k] - base);
            if (sl < SLOTS) {
                if (sl < 64) m0 &= ~(1ull << sl);
                else         m1 &= ~(1ull << (sl - 64));
            }
        }

        // ---- suppression sweep: new kept boxes vs this thread's live candidates ----
        unsigned long long hm0 = 0, hm1 = 0;
        for (int n = 0; n < nNew; ++n) {
            int bi = keptB[n];
            bool hit = (bbx1[bi] < tx2) && (bbx2[bi] > tx1) && (bby1[bi] < ty2) && (bby2[bi] > ty1);
            if (hit) { if (n < 64) hm0 |= 1ull << n; else hm1 |= 1ull << (n - 64); }
        }
        if (hm0 | hm1) {
            #pragma unroll
            for (int c = 0; c < SLOTS; ++c) {
                bool live = (c < 64) ? ((m0 >> c) & 1ull) : ((m1 >> (c - 64)) & 1ull);
                if (!live) continue;
                int o = orig_r[base + c];
                float4 cb = loc4[o];
                float ca = area_of(cb.x, cb.y, cb.z, cb.w);
                unsigned long long h0 = hm0, h1 = hm1;
                bool dead = false;
                while (h0 && !dead) {
                    int n = __builtin_ctzll(h0); h0 &= h0 - 1;
                    int bi = keptB[n];
                    dead = iou_gt_thr(bbx1[bi], bby1[bi], bbx2[bi], bby2[bi], bbar[bi],
                                      cb.x, cb.y, cb.z, cb.w, ca);
                }
                while (h1 && !dead) {
                    int n = __builtin_ctzll(h1) + 64; h1 &= h1 - 1;
                    int bi = keptB[n];
                    dead = iou_gt_thr(bbx1[bi], bby1[bi], bbx2[bi], bby2[bi], bbar[bi],
                                      cb.x, cb.y, cb.z, cb.w, ca);
                }
                if (dead) {
                    if (c < 64) m0 &= ~(1ull << c);
                    else        m1 &= ~(1ull << (c - 64));
                }
            }
        }
        if (keptTotal >= MAXDET) break;
        __syncthreads();
    }

    // ---- write outputs: boxes[512*4] | landms[512*10] | scores[512] ----
    __syncthreads();
    int keptTotal = ctrl[6];
    for (int k = tid; k < MAXDET; k += NT) {
        if (k < keptTotal) {
            int o = keptOrig[k];
            float4 b = loc4[o];
            out[4 * k + 0] = b.x; out[4 * k + 1] = b.y;
            out[4 * k + 2] = b.z; out[4 * k + 3] = b.w;
            #pragma unroll
            for (int j = 0; j < 10; ++j) out[2048 + 10 * k + j] = landms[10 * o + j];
            out[2048 + 5120 + k] = conf[2 * o + 1];
        } else {
            out[4 * k + 0] = 0.0f; out[4 * k + 1] = 0.0f;
            out[4 * k + 2] = 0.0f; out[4 * k + 3] = 0.0f;
            #pragma unroll
            for (int j = 0; j < 10; ++j) out[2048 + 10 * k + j] = 0.0f;
            out[2048 + 5120 + k] = 0.0f;
        }
    }
}

extern "C" void kernel_launch(void* const* d_in, const int* in_sizes, int n_in,
                              void* d_out, int out_size, void* d_ws, size_t ws_size,
                              hipStream_t stream) {
    const float* loc    = (const float*)d_in[0];   // [43008,4]
    const float* conf   = (const float*)d_in[1];   // [43008,2]
    const float* landms = (const float*)d_in[2];   // [43008,10]
    float* out = (float*)d_out;                    // 7680 floats

    unsigned int* tileCnt = (unsigned int*)d_ws;           // 1024 u32
    unsigned int* tileCur = tileCnt + 1024;                // 1024 u32
    int*          orig_r  = (int*)(tileCur + 1024);        // 43008 i32

    hipMemsetAsync(tileCnt, 0, 1024 * sizeof(unsigned int), stream);
    tile_hist_k<<<N_BOX / 256, 256, 0, stream>>>((const float4*)loc, tileCnt);
    tile_scan_k<<<1, 1024, 0, stream>>>(tileCnt, tileCur);
    tile_scatter_k<<<N_BOX / 256, 256, 0, stream>>>((const float4*)loc, tileCur, orig_r);
    nms_main_k<<<1, NT, 0, stream>>>(loc, conf, landms, orig_r, out);
}

// Round 5
// 442.068 us; speedup vs baseline: 7.2413x; 7.2413x over previous
//
#include <hip/hip_runtime.h>

#define N_BOX   43008
#define NT      1024
#define SLOTS_H 42          // N_BOX / NT
#define MAXDET  512
#define BATCH   128
#define CAP     2048
#define NBIN    1024
#define NMS_THR 0.4f

static_assert(NT * SLOTS_H == N_BOX, "slot mismatch");

typedef unsigned long long u64;
typedef unsigned int u32;

// ---------- exact-arithmetic helpers (match numpy f32, no FMA contraction) ----------
__device__ __forceinline__ float area_of(float x1, float y1, float x2, float y2) {
    return __fmul_rn(__fsub_rn(x2, x1), __fsub_rn(y2, y1));
}

// add/fmax/fmin are bitwise-commutative, so operand roles cannot change the decision
__device__ __forceinline__ bool iou_gt_thr(float ax1, float ay1, float ax2, float ay2, float aar,
                                           float bx1, float by1, float bx2, float by2, float bar) {
    float xx1 = fmaxf(ax1, bx1);
    float yy1 = fmaxf(ay1, by1);
    float xx2 = fminf(ax2, bx2);
    float yy2 = fminf(ay2, by2);
    float dx = __fsub_rn(xx2, xx1);
    float dy = __fsub_rn(yy2, yy1);
    if (dx <= 0.0f || dy <= 0.0f) return false;   // inter == 0 -> iou == 0, not > 0.4
    float inter = __fmul_rn(dx, dy);
    float denom = __fsub_rn(__fadd_rn(aar, bar), inter);  // areas[i] + areas[j] - inter
    return inter / denom > NMS_THR;               // IEEE f32 division (no fast-math)
}

// monotone score -> bin (s1 >= s2 => bin1 >= bin2); equal scores share a bin
__device__ __forceinline__ int bin_of(float s) {
    int b = (int)(s * 1024.0f);
    return b < 0 ? 0 : (b > 1023 ? 1023 : b);
}

enum { CT_KT = 0, CT_NN = 1, CT_CUR = 2, CT_BLO = 3 };

__global__ __launch_bounds__(NT, 1) void nms_topk_k(const float* __restrict__ loc,
                                                    const float* __restrict__ conf,
                                                    const float* __restrict__ landms,
                                                    float* __restrict__ out) {
    const float4* loc4 = (const float4*)loc;

    __shared__ u32    hist[NBIN];        // 4 KB
    __shared__ u32    suf[NBIN];         // 4 KB
    __shared__ u64    key[CAP];          // 16 KB  (~score_bits : idx) ascending = score desc, idx asc
    __shared__ float4 chBox[CAP];        // 32 KB
    __shared__ float  chArea[CAP];       // 8 KB
    __shared__ unsigned char dead[CAP];  // 2 KB
    __shared__ u32    mat[BATCH * 4];    // 2 KB   pairwise suppression bits (row i, bit j, i<j)
    __shared__ int    keptIdx[MAXDET];   // 2 KB
    __shared__ u32    keptSB[MAXDET];    // 2 KB   original score bits
    __shared__ float4 keptBox[MAXDET];   // 8 KB
    __shared__ float  keptArea[MAXDET];  // 2 KB
    __shared__ int    keptB[BATCH];      // batch-member indices of newly kept
    __shared__ int    ctrl[8];

    const int tid = threadIdx.x;

    // ---- one-time: cache scores in registers, build histogram ----
    float sc[SLOTS_H];
    hist[tid] = 0u;
    if (tid == 0) ctrl[CT_KT] = 0;
    __syncthreads();
    #pragma unroll
    for (int c = 0; c < SLOTS_H; ++c) {
        sc[c] = conf[2 * (tid + c * NT) + 1];   // coalesced stride-2
        atomicAdd(&hist[bin_of(sc[c])], 1u);
    }
    __syncthreads();
    // suffix sums: suf[b] = count of boxes with bin >= b
    suf[tid] = hist[tid];
    __syncthreads();
    for (int d = 1; d < NBIN; d <<= 1) {
        u32 v = (tid + d < NBIN) ? suf[tid + d] : 0u;
        __syncthreads();
        suf[tid] += v;
        __syncthreads();
    }

    // ---- chunk loop over descending score-bin ranges [blo, bhi) ----
    int bhi = NBIN;
    while (true) {
        int kt0 = ctrl[CT_KT];
        if (kt0 >= MAXDET || bhi <= 0) break;
        u32 base = (bhi >= NBIN) ? 0u : suf[bhi];
        if (tid == 0) { ctrl[CT_BLO] = bhi - 1; ctrl[CT_CUR] = 0; }
        __syncthreads();
        if (tid < bhi) {                            // smallest blo with count(blo..bhi) <= CAP
            u32 cnt = suf[tid] - base;
            u32 cprev = (tid == 0) ? 0xFFFFFFFFu : (suf[tid - 1] - base);
            if (cnt <= CAP && cprev > CAP) ctrl[CT_BLO] = tid;
        }
        __syncthreads();
        int blo = ctrl[CT_BLO]; if (blo >= bhi) blo = bhi - 1;   // forced progress

        // collect chunk members (bins [blo, bhi)) as sortable u64 keys
        #pragma unroll
        for (int c = 0; c < SLOTS_H; ++c) {
            int b = bin_of(sc[c]);
            if (b >= blo && b < bhi) {
                int pos = atomicAdd(&ctrl[CT_CUR], 1);
                if (pos < CAP) {
                    u32 sb = __float_as_uint(sc[c]);   // scores >= 0: bit order == float order
                    key[pos] = ((u64)(~sb) << 32) | (u32)(tid + c * NT);
                }
            }
        }
        __syncthreads();
        int M = ctrl[CT_CUR]; if (M > CAP) M = CAP;
        for (int r = M + tid; r < CAP; r += NT) key[r] = ~0ull;   // pad sorts last
        __syncthreads();
        // bitonic ascending sort (exact greedy order: score desc, idx asc)
        for (int k = 2; k <= CAP; k <<= 1) {
            for (int j = k >> 1; j > 0; j >>= 1) {
                int idx = ((tid & ~(j - 1)) << 1) | (tid & (j - 1));
                int pr  = idx | j;
                bool asc = ((idx & k) == 0);
                u64 a = key[idx], b = key[pr];
                if ((a > b) == asc) { key[idx] = b; key[pr] = a; }
                __syncthreads();
            }
        }
        // fetch boxes; init dead[] vs all kept so far (no-op for first chunk)
        for (int r = tid; r < M; r += NT) {
            int o = (int)(u32)(key[r] & 0xFFFFFFFFull);
            float4 b = loc4[o];
            chBox[r] = b;
            chArea[r] = area_of(b.x, b.y, b.z, b.w);
        }
        __syncthreads();
        for (int q = tid; q < M; q += NT) {
            float4 cb = chBox[q]; float ca = chArea[q];
            bool dd = false;
            for (int k2 = 0; k2 < kt0 && !dd; ++k2) {
                float4 kb = keptBox[k2];
                dd = iou_gt_thr(kb.x, kb.y, kb.z, kb.w, keptArea[k2],
                                cb.x, cb.y, cb.z, cb.w, ca);
            }
            dead[q] = dd ? 1 : 0;
        }
        __syncthreads();

        // ---- greedy rounds over sorted chunk, 128 positions per round ----
        for (int p0 = 0; p0 < M; p0 += BATCH) {
            if (ctrl[CT_KT] >= MAXDET) break;       // uniform (barrier-synced LDS read)
            int B = M - p0; if (B > BATCH) B = BATCH;
            if (tid < BATCH * 4) mat[tid] = 0u;
            __syncthreads();
            // pairwise suppression matrix within batch
            for (int p = tid; p < B * BATCH; p += NT) {
                int i = p >> 7, j = p & (BATCH - 1);
                if (i < j && j < B) {
                    float4 bi = chBox[p0 + i], bj = chBox[p0 + j];
                    if (iou_gt_thr(bi.x, bi.y, bi.z, bi.w, chArea[p0 + i],
                                   bj.x, bj.y, bj.z, bj.w, chArea[p0 + j]))
                        atomicOr(&mat[(i << 2) + (j >> 5)], 1u << (j & 31));
                }
            }
            __syncthreads();
            // wave-cooperative greedy bit-scan (lane L owns members L and L+64)
            if (tid < 64) {
                int L = tid;
                int kt = ctrl[CT_KT];
                bool mlo = (L < B) ? (dead[p0 + L] != 0) : true;
                bool mhi = (64 + L < B) ? (dead[p0 + 64 + L] != 0) : true;
                int nn = 0;
                for (int i = 0; i < B && kt < MAXDET; ++i) {
                    u64 bal = __ballot((i >> 6) ? mhi : mlo);
                    if (!((bal >> (i & 63)) & 1ull)) {
                        u32 rlo = mat[(i << 2) + (L >> 5)];
                        u32 rhi = mat[(i << 2) + 2 + (L >> 5)];
                        mlo = mlo || ((rlo >> (L & 31)) & 1u);
                        mhi = mhi || ((rhi >> (L & 31)) & 1u);
                        if (L == 0) {
                            u64 kk = key[p0 + i];
                            keptB[nn] = i;
                            keptIdx[kt] = (int)(u32)(kk & 0xFFFFFFFFull);
                            keptSB[kt] = ~(u32)(kk >> 32);
                            keptBox[kt] = chBox[p0 + i];
                            keptArea[kt] = chArea[p0 + i];
                        }
                        ++nn; ++kt;
                    }
                }
                if (L == 0) { ctrl[CT_KT] = kt; ctrl[CT_NN] = nn; }
            }
            __syncthreads();
            // sweep: new kept vs remaining chunk positions
            int nn = ctrl[CT_NN];
            if (ctrl[CT_KT] < MAXDET && nn > 0) {
                for (int q = p0 + B + tid; q < M; q += NT) {
                    if (dead[q]) continue;
                    float4 cb = chBox[q]; float ca = chArea[q];
                    bool dd = false;
                    for (int n = 0; n < nn && !dd; ++n) {
                        int bi = p0 + keptB[n];
                        float4 kb = chBox[bi];
                        dd = iou_gt_thr(kb.x, kb.y, kb.z, kb.w, chArea[bi],
                                        cb.x, cb.y, cb.z, cb.w, ca);
                    }
                    if (dd) dead[q] = 1;
                }
            }
            __syncthreads();
        }
        bhi = blo;
    }

    // ---- outputs: boxes[512*4] | landms[512*10] | scores[512] ----
    __syncthreads();
    int kt = ctrl[CT_KT];
    if (tid < MAXDET) {
        int k = tid;
        if (k < kt) {
            int o = keptIdx[k];
            float4 b = keptBox[k];
            *(float4*)(out + 4 * k) = b;
            #pragma unroll
            for (int j = 0; j < 10; ++j) out[2048 + 10 * k + j] = landms[10 * o + j];
            out[7168 + k] = __uint_as_float(keptSB[k]);
        } else {
            *(float4*)(out + 4 * k) = make_float4(0.f, 0.f, 0.f, 0.f);
            #pragma unroll
            for (int j = 0; j < 10; ++j) out[2048 + 10 * k + j] = 0.0f;
            out[7168 + k] = 0.0f;
        }
    }
}

extern "C" void kernel_launch(void* const* d_in, const int* in_sizes, int n_in,
                              void* d_out, int out_size, void* d_ws, size_t ws_size,
                              hipStream_t stream) {
    const float* loc    = (const float*)d_in[0];   // [43008,4]
    const float* conf   = (const float*)d_in[1];   // [43008,2]
    const float* landms = (const float*)d_in[2];   // [43008,10]
    float* out = (float*)d_out;                    // 7680 floats

    nms_topk_k<<<1, NT, 0, stream>>>(loc, conf, landms, out);
}

// Round 6
// 374.457 us; speedup vs baseline: 8.5488x; 1.1806x over previous
//
#include <hip/hip_runtime.h>

#define N_BOX   43008
#define NT      1024
#define SLOTS_H 42          // N_BOX / NT
#define MAXDET  512
#define BATCH   128
#define CAP     2048
#define NBIN    1024
#define NMS_THR 0.4f

static_assert(NT * SLOTS_H == N_BOX, "slot mismatch");

typedef unsigned long long u64;
typedef unsigned int u32;

// ---------- exact-arithmetic helpers (match numpy f32, no FMA contraction) ----------
__device__ __forceinline__ float area_of(float x1, float y1, float x2, float y2) {
    return __fmul_rn(__fsub_rn(x2, x1), __fsub_rn(y2, y1));
}

// add/fmax/fmin are bitwise-commutative, so operand roles cannot change the decision
__device__ __forceinline__ bool iou_gt_thr(float ax1, float ay1, float ax2, float ay2, float aar,
                                           float bx1, float by1, float bx2, float by2, float bar) {
    float xx1 = fmaxf(ax1, bx1);
    float yy1 = fmaxf(ay1, by1);
    float xx2 = fminf(ax2, bx2);
    float yy2 = fminf(ay2, by2);
    float dx = __fsub_rn(xx2, xx1);
    float dy = __fsub_rn(yy2, yy1);
    if (dx <= 0.0f || dy <= 0.0f) return false;   // inter == 0 -> iou == 0, not > 0.4
    float inter = __fmul_rn(dx, dy);
    float denom = __fsub_rn(__fadd_rn(aar, bar), inter);  // areas[i] + areas[j] - inter
    return inter / denom > NMS_THR;               // IEEE f32 division (no fast-math)
}

// monotone score -> bin (s1 >= s2 => bin1 >= bin2); equal scores share a bin
__device__ __forceinline__ int bin_of(float s) {
    int b = (int)(s * 1024.0f);
    return b < 0 ? 0 : (b > 1023 ? 1023 : b);
}

enum { CT_KT = 0, CT_NN = 1, CT_BLO = 2 };

__global__ __launch_bounds__(NT, 1) void nms_topk_k(const float* __restrict__ loc,
                                                    const float* __restrict__ conf,
                                                    const float* __restrict__ landms,
                                                    float* __restrict__ out) {
    const float4* loc4 = (const float4*)loc;

    __shared__ u32    hist[NBIN];        // 4 KB   per-bin counts (immutable after build)
    __shared__ u32    suf[NBIN];         // 4 KB   suffix sums
    __shared__ u32    cur[NBIN];         // 4 KB   per-bin scatter cursors
    __shared__ u64    keyA[CAP];         // 16 KB  bin-segmented (unsorted within bin)
    __shared__ u64    key[CAP];          // 16 KB  fully sorted (score desc, idx asc)
    __shared__ float4 chBox[CAP];        // 32 KB
    __shared__ float  chArea[CAP];       // 8 KB
    __shared__ unsigned char dead[CAP];  // 2 KB
    __shared__ u32    matT[BATCH * 4];   // 2 KB   transposed: matT[j] bits over suppressors i<j
    __shared__ int    keptIdx[MAXDET];   // 2 KB
    __shared__ u32    keptSB[MAXDET];    // 2 KB   original score bits
    __shared__ float4 keptBox[MAXDET];   // 8 KB
    __shared__ float  keptArea[MAXDET];  // 2 KB
    __shared__ int    keptB[BATCH];      // batch-member positions of newly kept
    __shared__ int    ctrl[8];

    const int tid = threadIdx.x;

    // ---- one-time: cache scores in registers, build histogram ----
    float sc[SLOTS_H];
    hist[tid] = 0u;
    if (tid == 0) ctrl[CT_KT] = 0;
    __syncthreads();
    #pragma unroll
    for (int c = 0; c < SLOTS_H; ++c) {
        sc[c] = conf[2 * (tid + c * NT) + 1];   // coalesced stride-2
        atomicAdd(&hist[bin_of(sc[c])], 1u);
    }
    __syncthreads();
    // suffix sums: suf[b] = count of boxes with bin >= b
    suf[tid] = hist[tid];
    __syncthreads();
    for (int d = 1; d < NBIN; d <<= 1) {
        u32 v = (tid + d < NBIN) ? suf[tid + d] : 0u;
        __syncthreads();
        suf[tid] += v;
        __syncthreads();
    }

    // ---- chunk loop over descending score-bin ranges [blo, bhi) ----
    int bhi = NBIN;
    while (true) {
        int kt0 = ctrl[CT_KT];
        if (kt0 >= MAXDET || bhi <= 0) break;
        u32 base = (bhi >= NBIN) ? 0u : suf[bhi];
        cur[tid] = 0u;
        if (tid == 0) ctrl[CT_BLO] = bhi - 1;
        __syncthreads();
        if (tid < bhi) {                            // smallest blo with count(blo..bhi) <= CAP
            u32 cnt = suf[tid] - base;
            u32 cprev = (tid == 0) ? 0xFFFFFFFFu : (suf[tid - 1] - base);
            if (cnt <= CAP && cprev > CAP) ctrl[CT_BLO] = tid;
        }
        __syncthreads();
        int blo = ctrl[CT_BLO]; if (blo >= bhi) blo = bhi - 1;   // forced progress
        int M = (int)(suf[blo] - base); if (M > CAP) M = CAP;

        // ---- scatter chunk members into per-bin segments (descending-bin layout) ----
        #pragma unroll
        for (int c = 0; c < SLOTS_H; ++c) {
            int b = bin_of(sc[c]);
            if (b >= blo && b < bhi) {
                u32 segStart = (((b + 1) >= NBIN) ? 0u : suf[b + 1]) - base;
                u32 slot = segStart + atomicAdd(&cur[b], 1u);
                if (slot < (u32)CAP) {
                    u32 sb = __float_as_uint(sc[c]);   // scores >= 0: bit order == float order
                    keyA[slot] = ((u64)(~sb) << 32) | (u32)(tid + c * NT);
                }
            }
        }
        __syncthreads();

        // ---- per-bin rank sort (exact key order within each ~42-element segment) ----
        u64 myKey0 = 0, myKey1 = 0; int myPos0 = -1, myPos1 = -1;
        {
            int r = tid;
            if (r < M) {
                u64 k = keyA[r];
                u32 sb = ~(u32)(k >> 32);
                int b = bin_of(__uint_as_float(sb));
                int s0 = (int)((((b + 1) >= NBIN) ? 0u : suf[b + 1]) - base);
                int e0 = s0 + (int)hist[b]; if (e0 > M) e0 = M;
                int rank = s0;
                for (int q = s0; q < e0; ++q) rank += (keyA[q] < k) ? 1 : 0;
                myKey0 = k; myPos0 = rank;
            }
            r = tid + NT;
            if (r < M) {
                u64 k = keyA[r];
                u32 sb = ~(u32)(k >> 32);
                int b = bin_of(__uint_as_float(sb));
                int s0 = (int)((((b + 1) >= NBIN) ? 0u : suf[b + 1]) - base);
                int e0 = s0 + (int)hist[b]; if (e0 > M) e0 = M;
                int rank = s0;
                for (int q = s0; q < e0; ++q) rank += (keyA[q] < k) ? 1 : 0;
                myKey1 = k; myPos1 = rank;
            }
        }
        if (myPos0 >= 0 && myPos0 < CAP) key[myPos0] = myKey0;
        if (myPos1 >= 0 && myPos1 < CAP) key[myPos1] = myKey1;
        __syncthreads();

        // ---- fetch boxes; init dead[] vs all kept so far ----
        for (int r = tid; r < M; r += NT) {
            int o = (int)(u32)(key[r] & 0xFFFFFFFFull);
            float4 b = loc4[o];
            chBox[r] = b;
            chArea[r] = area_of(b.x, b.y, b.z, b.w);
        }
        __syncthreads();
        for (int q = tid; q < M; q += NT) {
            float4 cb = chBox[q]; float ca = chArea[q];
            bool dd = false;
            for (int k2 = 0; k2 < kt0 && !dd; ++k2) {
                float4 kb = keptBox[k2];
                dd = iou_gt_thr(kb.x, kb.y, kb.z, kb.w, keptArea[k2],
                                cb.x, cb.y, cb.z, cb.w, ca);
            }
            dead[q] = dd ? 1 : 0;
        }
        __syncthreads();

        // ---- greedy rounds over sorted chunk, 128 positions per round ----
        for (int p0 = 0; p0 < M; p0 += BATCH) {
            if (ctrl[CT_KT] >= MAXDET) break;       // uniform (barrier-synced LDS read)
            int B = M - p0; if (B > BATCH) B = BATCH;
            if (tid < BATCH * 4) matT[tid] = 0u;
            __syncthreads();
            // transposed pairwise suppression matrix within batch (bits over i, row j)
            for (int p = tid; p < B * BATCH; p += NT) {
                int i = p >> 7, j = p & (BATCH - 1);
                if (i < j && j < B) {
                    float4 bi = chBox[p0 + i], bj = chBox[p0 + j];
                    if (iou_gt_thr(bi.x, bi.y, bi.z, bi.w, chArea[p0 + i],
                                   bj.x, bj.y, bj.z, bj.w, chArea[p0 + j]))
                        atomicOr(&matT[(j << 2) + (i >> 5)], 1u << (i & 31));
                }
            }
            __syncthreads();
            // wave-cooperative greedy scan: register-resident columns, pure-VALU chain
            if (tid < 64) {
                const int L = tid;
                int ktBase = ctrl[CT_KT];
                u64 cl0 = ((u64)matT[(L << 2) + 1] << 32) | matT[(L << 2) + 0];        // member L,    i 0..63
                u64 ch0 = ((u64)matT[(L << 2) + 3] << 32) | matT[(L << 2) + 2];        // member L,    i 64..127
                u64 cl1 = ((u64)matT[((L + 64) << 2) + 1] << 32) | matT[((L + 64) << 2) + 0];
                u64 ch1 = ((u64)matT[((L + 64) << 2) + 3] << 32) | matT[((L + 64) << 2) + 2];
                u32 dlo = (L < B)      ? (u32)dead[p0 + L]      : 1u;
                u32 dhi = (64 + L < B) ? (u32)dead[p0 + 64 + L] : 1u;
                int kt = ktBase;
                int i = 0;
                for (; i < B && kt < MAXDET; ++i) {
                    u64 bal = __ballot((i & 64) ? (dhi != 0u) : (dlo != 0u));
                    if (!((bal >> (i & 63)) & 1ull)) {
                        dlo |= (u32)(((i & 64) ? ch0 : cl0) >> (i & 63)) & 1u;
                        dhi |= (u32)(((i & 64) ? ch1 : cl1) >> (i & 63)) & 1u;
                        ++kt;
                    }
                }
                int iStop = i;   // positions >= iStop were not processed (cap reached)
                // final alive == kept (suppressors only have i<j); collect in position order
                u64 bal0 = __ballot((dlo == 0u) && (L < iStop));
                u64 bal1 = __ballot((dhi == 0u) && (64 + L < iStop));
                int n0 = __popcll(bal0);
                if ((bal0 >> L) & 1ull) {
                    int n = __popcll(bal0 & ((1ull << L) - 1ull));
                    int pos = p0 + L;
                    u64 kk = key[pos];
                    keptB[n] = L;
                    keptIdx[ktBase + n] = (int)(u32)(kk & 0xFFFFFFFFull);
                    keptSB[ktBase + n] = ~(u32)(kk >> 32);
                    keptBox[ktBase + n] = chBox[pos];
                    keptArea[ktBase + n] = chArea[pos];
                }
                if ((bal1 >> L) & 1ull) {
                    int n = n0 + __popcll(bal1 & ((1ull << L) - 1ull));
                    int pos = p0 + 64 + L;
                    u64 kk = key[pos];
                    keptB[n] = 64 + L;
                    keptIdx[ktBase + n] = (int)(u32)(kk & 0xFFFFFFFFull);
                    keptSB[ktBase + n] = ~(u32)(kk >> 32);
                    keptBox[ktBase + n] = chBox[pos];
                    keptArea[ktBase + n] = chArea[pos];
                }
                if (L == 0) {
                    int nn = n0 + __popcll(bal1);
                    ctrl[CT_KT] = ktBase + nn;
                    ctrl[CT_NN] = nn;
                }
            }
            __syncthreads();
            // sweep: new kept vs remaining chunk positions
            int nn = ctrl[CT_NN];
            if (ctrl[CT_KT] < MAXDET && nn > 0) {
                for (int q = p0 + B + tid; q < M; q += NT) {
                    if (dead[q]) continue;
                    float4 cb = chBox[q]; float ca = chArea[q];
                    bool dd = false;
                    for (int n = 0; n < nn && !dd; ++n) {
                        int bi = p0 + keptB[n];
                        float4 kb = chBox[bi];
                        dd = iou_gt_thr(kb.x, kb.y, kb.z, kb.w, chArea[bi],
                                        cb.x, cb.y, cb.z, cb.w, ca);
                    }
                    if (dd) dead[q] = 1;
                }
            }
            __syncthreads();
        }
        bhi = blo;
    }

    // ---- outputs: boxes[512*4] | landms[512*10] | scores[512] ----
    __syncthreads();
    int kt = ctrl[CT_KT];
    if (tid < MAXDET) {
        int k = tid;
        if (k < kt) {
            int o = keptIdx[k];
            float4 b = keptBox[k];
            *(float4*)(out + 4 * k) = b;
            #pragma unroll
            for (int j = 0; j < 10; ++j) out[2048 + 10 * k + j] = landms[10 * o + j];
            out[7168 + k] = __uint_as_float(keptSB[k]);
        } else {
            *(float4*)(out + 4 * k) = make_float4(0.f, 0.f, 0.f, 0.f);
            #pragma unroll
            for (int j = 0; j < 10; ++j) out[2048 + 10 * k + j] = 0.0f;
            out[7168 + k] = 0.0f;
        }
    }
}

extern "C" void kernel_launch(void* const* d_in, const int* in_sizes, int n_in,
                              void* d_out, int out_size, void* d_ws, size_t ws_size,
                              hipStream_t stream) {
    const float* loc    = (const float*)d_in[0];   // [43008,4]
    const float* conf   = (const float*)d_in[1];   // [43008,2]
    const float* landms = (const float*)d_in[2];   // [43008,10]
    float* out = (float*)d_out;                    // 7680 floats

    nms_topk_k<<<1, NT, 0, stream>>>(loc, conf, landms, out);
}

// Round 7
// 343.336 us; speedup vs baseline: 9.3237x; 1.0906x over previous
//
#include <hip/hip_runtime.h>

#define N_BOX   43008
#define NT      1024
#define MAXDET  512
#define BATCH   128
#define CAP     2048
#define NBIN    1024
#define NMS_THR 0.4f

typedef unsigned long long u64;
typedef unsigned int u32;

// ---------- exact-arithmetic helpers (match numpy f32, no FMA contraction) ----------
__device__ __forceinline__ float area_of(float x1, float y1, float x2, float y2) {
    return __fmul_rn(__fsub_rn(x2, x1), __fsub_rn(y2, y1));
}

// add/fmax/fmin are bitwise-commutative, so operand roles cannot change the decision
__device__ __forceinline__ bool iou_gt_thr(float ax1, float ay1, float ax2, float ay2, float aar,
                                           float bx1, float by1, float bx2, float by2, float bar) {
    float xx1 = fmaxf(ax1, bx1);
    float yy1 = fmaxf(ay1, by1);
    float xx2 = fminf(ax2, bx2);
    float yy2 = fminf(ay2, by2);
    float dx = __fsub_rn(xx2, xx1);
    float dy = __fsub_rn(yy2, yy1);
    if (dx <= 0.0f || dy <= 0.0f) return false;   // inter == 0 -> iou == 0, not > 0.4
    float inter = __fmul_rn(dx, dy);
    float denom = __fsub_rn(__fadd_rn(aar, bar), inter);  // areas[i] + areas[j] - inter
    return inter / denom > NMS_THR;               // IEEE f32 division (no fast-math)
}

// monotone score -> bin (s1 >= s2 => bin1 >= bin2); equal scores share a bin
__device__ __forceinline__ int bin_of(float s) {
    int b = (int)(s * 1024.0f);
    return b < 0 ? 0 : (b > 1023 ? 1023 : b);
}

// ---------- k1: global histogram of score bins ----------
__global__ void hist_k(const float* __restrict__ conf, u32* __restrict__ histG) {
    int i = blockIdx.x * 256 + threadIdx.x;
    if (i < N_BOX) atomicAdd(&histG[bin_of(conf[2 * i + 1])], 1u);
}

// ---------- k2: suffix scan + descending-bin scatter cursors ----------
__global__ __launch_bounds__(1024) void scan_k(const u32* __restrict__ histG,
                                               u32* __restrict__ sufG,
                                               u32* __restrict__ curG) {
    __shared__ u32 a[NBIN];
    int t = threadIdx.x;
    a[t] = histG[t];
    __syncthreads();
    for (int d = 1; d < NBIN; d <<= 1) {
        u32 v = (t + d < NBIN) ? a[t + d] : 0u;
        __syncthreads();
        a[t] += v;
        __syncthreads();
    }
    sufG[t] = a[t];                               // suf[b] = count of bins >= b
    curG[t] = (t + 1 >= NBIN) ? 0u : a[t + 1];    // descending layout: bin b starts at suf[b+1]
}

// ---------- k3: counting-sort scatter (key + box + area) into bin segments ----------
__global__ void scatter_k(const float* __restrict__ loc, const float* __restrict__ conf,
                          u32* __restrict__ curG, u64* __restrict__ wsKey,
                          float4* __restrict__ wsBox, float* __restrict__ wsArea) {
    int i = blockIdx.x * 256 + threadIdx.x;
    if (i >= N_BOX) return;
    float s = conf[2 * i + 1];
    u32 slot = atomicAdd(&curG[bin_of(s)], 1u);
    u32 sb = __float_as_uint(s);                  // scores >= 0: bit order == float order
    wsKey[slot] = ((u64)(~sb) << 32) | (u32)i;
    float4 b = ((const float4*)loc)[i];
    wsBox[slot] = b;
    wsArea[slot] = area_of(b.x, b.y, b.z, b.w);
}

enum { CT_KT = 0, CT_NN = 1, CT_BLO = 2 };

// ---------- k4: sequential greedy NMS over top chunk(s); O(CAP) work only ----------
__global__ __launch_bounds__(NT, 1) void nms_k(const u32* __restrict__ histG,
                                               const u32* __restrict__ sufG,
                                               const u64* __restrict__ wsKey,
                                               const float4* __restrict__ wsBox,
                                               const float* __restrict__ wsArea,
                                               const float* __restrict__ conf,
                                               const float* __restrict__ landms,
                                               float* __restrict__ out) {
    __shared__ u32    hist[NBIN];        // 4 KB
    __shared__ u32    suf[NBIN];         // 4 KB
    __shared__ u64    keyA[CAP];         // 16 KB  staged (bin-segmented, unsorted in bin)
    __shared__ u64    key[CAP];          // 16 KB  sorted (score desc, idx asc)
    __shared__ float4 chBox[CAP];        // 32 KB
    __shared__ float  chArea[CAP];       // 8 KB
    __shared__ unsigned char dead[CAP];  // 2 KB
    __shared__ u32    matT[BATCH * 4];   // 2 KB   transposed: matT[j] bits over suppressors i<j
    __shared__ int    keptIdx[MAXDET];
    __shared__ u32    keptSB[MAXDET];
    __shared__ float4 keptBox[MAXDET];
    __shared__ float  keptArea[MAXDET];
    __shared__ int    keptB[BATCH];
    __shared__ int    ctrl[8];

    const int tid = threadIdx.x;
    hist[tid] = histG[tid];
    suf[tid] = sufG[tid];
    if (tid == 0) ctrl[CT_KT] = 0;
    __syncthreads();

    int bhi = NBIN;
    while (true) {
        int kt0 = ctrl[CT_KT];
        if (kt0 >= MAXDET || bhi <= 0) break;
        u32 base = (bhi >= NBIN) ? 0u : suf[bhi];
        if (tid == 0) ctrl[CT_BLO] = bhi - 1;
        __syncthreads();
        if (tid < bhi) {                            // smallest blo with count(blo..bhi) <= CAP
            u32 cnt = suf[tid] - base;
            u32 cprev = (tid == 0) ? 0xFFFFFFFFu : (suf[tid - 1] - base);
            if (cnt <= CAP && cprev > CAP) ctrl[CT_BLO] = tid;
        }
        __syncthreads();
        int blo = ctrl[CT_BLO]; if (blo >= bhi) blo = bhi - 1;   // forced progress
        int M = (int)(suf[blo] - base); if (M > CAP) M = CAP;

        // stage chunk keys (coalesced; written by scatter_k just before -> L2-hot)
        for (int r = tid; r < M; r += NT) keyA[r] = wsKey[base + r];
        __syncthreads();

        // per-bin rank sort: exact (score desc, idx asc) within each ~42-elem segment
        #pragma unroll
        for (int rr = 0; rr < 2; ++rr) {
            int r = tid + rr * NT;
            if (r < M) {
                u64 k = keyA[r];
                u32 sb = ~(u32)(k >> 32);
                int b = bin_of(__uint_as_float(sb));
                int s0 = (int)((((b + 1) >= NBIN) ? 0u : suf[b + 1]) - base);
                int e0 = s0 + (int)hist[b]; if (e0 > M) e0 = M;
                int rank = s0;
                for (int q = s0; q < e0; ++q) rank += (keyA[q] < k) ? 1 : 0;
                if (rank < CAP) {
                    key[rank] = k;
                    chBox[rank] = wsBox[base + r];
                    chArea[rank] = wsArea[base + r];
                }
            }
        }
        __syncthreads();

        // init dead[] vs all kept so far (no-op for first chunk)
        for (int q = tid; q < M; q += NT) {
            bool dd = false;
            if (kt0 > 0) {
                float4 cb = chBox[q]; float ca = chArea[q];
                for (int k2 = 0; k2 < kt0 && !dd; ++k2) {
                    float4 kb = keptBox[k2];
                    dd = iou_gt_thr(kb.x, kb.y, kb.z, kb.w, keptArea[k2],
                                    cb.x, cb.y, cb.z, cb.w, ca);
                }
            }
            dead[q] = dd ? 1 : 0;
        }
        __syncthreads();

        // ---- greedy rounds over sorted chunk, 128 positions per round ----
        for (int p0 = 0; p0 < M; p0 += BATCH) {
            if (ctrl[CT_KT] >= MAXDET) break;       // uniform (barrier-synced LDS read)
            int B = M - p0; if (B > BATCH) B = BATCH;
            if (tid < BATCH * 4) matT[tid] = 0u;
            __syncthreads();
            // transposed pairwise suppression matrix within batch (row j, bits over i<j)
            for (int p = tid; p < B * BATCH; p += NT) {
                int i = p >> 7, j = p & (BATCH - 1);
                if (i < j && j < B) {
                    float4 bi = chBox[p0 + i], bj = chBox[p0 + j];
                    if (iou_gt_thr(bi.x, bi.y, bi.z, bi.w, chArea[p0 + i],
                                   bj.x, bj.y, bj.z, bj.w, chArea[p0 + j]))
                        atomicOr(&matT[(j << 2) + (i >> 5)], 1u << (i & 31));
                }
            }
            __syncthreads();
            // wave-cooperative greedy scan: register-resident columns, pure-VALU chain
            if (tid < 64) {
                const int L = tid;
                int ktBase = ctrl[CT_KT];
                u64 cl0 = ((u64)matT[(L << 2) + 1] << 32) | matT[(L << 2) + 0];
                u64 ch0 = ((u64)matT[(L << 2) + 3] << 32) | matT[(L << 2) + 2];
                u64 cl1 = ((u64)matT[((L + 64) << 2) + 1] << 32) | matT[((L + 64) << 2) + 0];
                u64 ch1 = ((u64)matT[((L + 64) << 2) + 3] << 32) | matT[((L + 64) << 2) + 2];
                u32 dlo = (L < B)      ? (u32)dead[p0 + L]      : 1u;
                u32 dhi = (64 + L < B) ? (u32)dead[p0 + 64 + L] : 1u;
                int kt = ktBase;
                int i = 0;
                for (; i < B && kt < MAXDET; ++i) {
                    u64 bal = __ballot((i & 64) ? (dhi != 0u) : (dlo != 0u));
                    if (!((bal >> (i & 63)) & 1ull)) {
                        dlo |= (u32)(((i & 64) ? ch0 : cl0) >> (i & 63)) & 1u;
                        dhi |= (u32)(((i & 64) ? ch1 : cl1) >> (i & 63)) & 1u;
                        ++kt;
                    }
                }
                int iStop = i;   // positions >= iStop were not processed (cap reached)
                // final alive == kept (suppressors only have i<j); collect in position order
                u64 bal0 = __ballot((dlo == 0u) && (L < iStop));
                u64 bal1 = __ballot((dhi == 0u) && (64 + L < iStop));
                int n0 = __popcll(bal0);
                if ((bal0 >> L) & 1ull) {
                    int n = __popcll(bal0 & ((1ull << L) - 1ull));
                    int pos = p0 + L;
                    u64 kk = key[pos];
                    keptB[n] = L;
                    keptIdx[ktBase + n] = (int)(u32)(kk & 0xFFFFFFFFull);
                    keptSB[ktBase + n] = ~(u32)(kk >> 32);
                    keptBox[ktBase + n] = chBox[pos];
                    keptArea[ktBase + n] = chArea[pos];
                }
                if ((bal1 >> L) & 1ull) {
                    int n = n0 + __popcll(bal1 & ((1ull << L) - 1ull));
                    int pos = p0 + 64 + L;
                    u64 kk = key[pos];
                    keptB[n] = 64 + L;
                    keptIdx[ktBase + n] = (int)(u32)(kk & 0xFFFFFFFFull);
                    keptSB[ktBase + n] = ~(u32)(kk >> 32);
                    keptBox[ktBase + n] = chBox[pos];
                    keptArea[ktBase + n] = chArea[pos];
                }
                if (L == 0) {
                    int nn = n0 + __popcll(bal1);
                    ctrl[CT_KT] = ktBase + nn;
                    ctrl[CT_NN] = nn;
                }
            }
            __syncthreads();
            // sweep: new kept vs remaining chunk positions
            int nn = ctrl[CT_NN];
            if (ctrl[CT_KT] < MAXDET && nn > 0) {
                for (int q = p0 + B + tid; q < M; q += NT) {
                    if (dead[q]) continue;
                    float4 cb = chBox[q]; float ca = chArea[q];
                    bool dd = false;
                    for (int n = 0; n < nn && !dd; ++n) {
                        int bi = p0 + keptB[n];
                        float4 kb = chBox[bi];
                        dd = iou_gt_thr(kb.x, kb.y, kb.z, kb.w, chArea[bi],
                                        cb.x, cb.y, cb.z, cb.w, ca);
                    }
                    if (dd) dead[q] = 1;
                }
            }
            __syncthreads();
        }
        bhi = blo;
    }

    // ---- outputs: boxes[512*4] | landms[512*10] | scores[512] ----
    __syncthreads();
    int kt = ctrl[CT_KT];
    if (tid < MAXDET) {
        int k = tid;
        if (k < kt) {
            int o = keptIdx[k];
            float4 b = keptBox[k];
            *(float4*)(out + 4 * k) = b;
            #pragma unroll
            for (int j = 0; j < 10; ++j) out[2048 + 10 * k + j] = landms[10 * o + j];
            out[7168 + k] = __uint_as_float(keptSB[k]);
        } else {
            *(float4*)(out + 4 * k) = make_float4(0.f, 0.f, 0.f, 0.f);
            #pragma unroll
            for (int j = 0; j < 10; ++j) out[2048 + 10 * k + j] = 0.0f;
            out[7168 + k] = 0.0f;
        }
    }
}

extern "C" void kernel_launch(void* const* d_in, const int* in_sizes, int n_in,
                              void* d_out, int out_size, void* d_ws, size_t ws_size,
                              hipStream_t stream) {
    const float* loc    = (const float*)d_in[0];   // [43008,4]
    const float* conf   = (const float*)d_in[1];   // [43008,2]
    const float* landms = (const float*)d_in[2];   // [43008,10]
    float* out = (float*)d_out;                    // 7680 floats

    char* ws = (char*)d_ws;
    u32*    histG  = (u32*)(ws + 0);          // 4 KB
    u32*    sufG   = (u32*)(ws + 4096);       // 4 KB
    u32*    curG   = (u32*)(ws + 8192);       // 4 KB
    u64*    wsKey  = (u64*)(ws + 12288);      // 344064 B
    float4* wsBox  = (float4*)(ws + 356352);  // 688128 B
    float*  wsArea = (float*)(ws + 1044480);  // 172032 B  (total ~1.19 MB)

    hipMemsetAsync(histG, 0, NBIN * sizeof(u32), stream);
    hist_k<<<N_BOX / 256, 256, 0, stream>>>(conf, histG);
    scan_k<<<1, 1024, 0, stream>>>(histG, sufG, curG);
    scatter_k<<<N_BOX / 256, 256, 0, stream>>>(loc, conf, curG, wsKey, wsBox, wsArea);
    nms_k<<<1, NT, 0, stream>>>(histG, sufG, wsKey, wsBox, wsArea, conf, landms, out);
}

// Round 9
// 323.049 us; speedup vs baseline: 9.9092x; 1.0628x over previous
//
#include <hip/hip_runtime.h>

#define N_BOX   43008
#define NT      1024
#define MAXDET  512
#define BATCH   256
#define CAP     2048
#define NBIN    1024
#define NMS_THR 0.4f

typedef unsigned long long u64;
typedef unsigned int u32;

// ---------- exact-arithmetic helpers (match numpy f32, no FMA contraction) ----------
__device__ __forceinline__ float area_of(float x1, float y1, float x2, float y2) {
    return __fmul_rn(__fsub_rn(x2, x1), __fsub_rn(y2, y1));
}

// add/fmax/fmin are bitwise-commutative, so operand roles cannot change the decision
__device__ __forceinline__ bool iou_gt_thr(float ax1, float ay1, float ax2, float ay2, float aar,
                                           float bx1, float by1, float bx2, float by2, float bar) {
    float xx1 = fmaxf(ax1, bx1);
    float yy1 = fmaxf(ay1, by1);
    float xx2 = fminf(ax2, bx2);
    float yy2 = fminf(ay2, by2);
    float dx = __fsub_rn(xx2, xx1);
    float dy = __fsub_rn(yy2, yy1);
    if (dx <= 0.0f || dy <= 0.0f) return false;   // inter == 0 -> iou == 0, not > 0.4
    float inter = __fmul_rn(dx, dy);
    float denom = __fsub_rn(__fadd_rn(aar, bar), inter);  // areas[i] + areas[j] - inter
    return inter / denom > NMS_THR;               // IEEE f32 division (no fast-math)
}

// monotone score -> bin (s1 >= s2 => bin1 >= bin2); equal scores share a bin
__device__ __forceinline__ int bin_of(float s) {
    int b = (int)(s * 1024.0f);
    return b < 0 ? 0 : (b > 1023 ? 1023 : b);
}

// ---------- k1: global histogram of score bins ----------
__global__ void hist_k(const float* __restrict__ conf, u32* __restrict__ histG) {
    int i = blockIdx.x * 256 + threadIdx.x;
    if (i < N_BOX) atomicAdd(&histG[bin_of(conf[2 * i + 1])], 1u);
}

// ---------- k2: suffix scan + descending-bin scatter cursors ----------
__global__ __launch_bounds__(1024) void scan_k(const u32* __restrict__ histG,
                                               u32* __restrict__ sufG,
                                               u32* __restrict__ curG) {
    __shared__ u32 a[NBIN];
    int t = threadIdx.x;
    a[t] = histG[t];
    __syncthreads();
    for (int d = 1; d < NBIN; d <<= 1) {
        u32 v = (t + d < NBIN) ? a[t + d] : 0u;
        __syncthreads();
        a[t] += v;
        __syncthreads();
    }
    sufG[t] = a[t];                               // suf[b] = count of bins >= b
    curG[t] = (t + 1 >= NBIN) ? 0u : a[t + 1];    // descending layout: bin b starts at suf[b+1]
}

// ---------- k3: counting-sort scatter of keys into bin segments ----------
__global__ void scatter_k(const float* __restrict__ conf, u32* __restrict__ curG,
                          u64* __restrict__ wsKey) {
    int i = blockIdx.x * 256 + threadIdx.x;
    if (i >= N_BOX) return;
    float s = conf[2 * i + 1];
    u32 slot = atomicAdd(&curG[bin_of(s)], 1u);
    u32 sb = __float_as_uint(s);                  // scores >= 0: bit order == float order
    wsKey[slot] = ((u64)(~sb) << 32) | (u32)i;
}

enum { CT_KT = 0, CT_NN = 1, CT_BLO = 2 };

// ---------- k4: sequential greedy NMS over top chunk(s); O(CAP) work only ----------
__global__ __launch_bounds__(NT, 1) void nms_k(const u32* __restrict__ sufG,
                                               const u64* __restrict__ wsKey,
                                               const float* __restrict__ loc,
                                               const float* __restrict__ landms,
                                               float* __restrict__ out) {
    const float4* loc4 = (const float4*)loc;

    __shared__ u32    suf[NBIN];         // 4 KB
    __shared__ u64    keyA[CAP];         // 16 KB  staged (bin-segmented, unsorted in bin)
    __shared__ u64    key[CAP];          // 16 KB  sorted (score desc, idx asc)
    __shared__ float4 chBox[CAP];        // 32 KB
    __shared__ float  chArea[CAP];       // 8 KB
    __shared__ unsigned char dead[CAP];  // 2 KB
    __shared__ u32    matT[BATCH * 8];   // 8 KB   transposed: row j = 256 bits over suppressors i<j
    __shared__ int    keptIdx[MAXDET];   // 2 KB
    __shared__ u32    keptSB[MAXDET];    // 2 KB
    __shared__ float4 keptBox[MAXDET];   // 8 KB
    __shared__ float  keptArea[MAXDET];  // 2 KB
    __shared__ int    keptB[BATCH];      // 1 KB   batch-relative positions of newly kept
    __shared__ int    ctrl[8];

    const int tid = threadIdx.x;
    suf[tid] = sufG[tid];
    if (tid == 0) ctrl[CT_KT] = 0;
    __syncthreads();

    int bhi = NBIN;
    while (true) {
        int kt0 = ctrl[CT_KT];
        if (kt0 >= MAXDET || bhi <= 0) break;
        u32 base = (bhi >= NBIN) ? 0u : suf[bhi];
        if (tid == 0) ctrl[CT_BLO] = bhi - 1;
        __syncthreads();
        if (tid < bhi) {                            // smallest blo with count(blo..bhi) <= CAP
            u32 cnt = suf[tid] - base;
            u32 cprev = (tid == 0) ? 0xFFFFFFFFu : (suf[tid - 1] - base);
            if (cnt <= CAP && cprev > CAP) ctrl[CT_BLO] = tid;
        }
        __syncthreads();
        int blo = ctrl[CT_BLO]; if (blo >= bhi) blo = bhi - 1;   // forced progress
        int M = (int)(suf[blo] - base); if (M > CAP) M = CAP;

        // stage chunk keys (coalesced; L2-hot from scatter_k)
        for (int r = tid; r < M; r += NT) keyA[r] = wsKey[base + r];
        __syncthreads();

        // per-bin rank sort: exact (score desc, idx asc) within each ~42-elem segment
        #pragma unroll
        for (int rr = 0; rr < 2; ++rr) {
            int r = tid + rr * NT;
            if (r < M) {
                u64 k = keyA[r];
                u32 sb = ~(u32)(k >> 32);
                int b = bin_of(__uint_as_float(sb));
                int s0 = (int)((((b + 1) >= NBIN) ? 0u : suf[b + 1]) - base);
                int e0 = (int)(suf[b] - base); if (e0 > M) e0 = M;
                int rank = s0;
                for (int q = s0; q < e0; ++q) rank += (keyA[q] < k) ? 1 : 0;
                if (rank < CAP) key[rank] = k;
            }
        }
        __syncthreads();

        // gather boxes (random 16B loads, L2/L3-hot) + compute areas
        for (int r = tid; r < M; r += NT) {
            int o = (int)(u32)(key[r] & 0xFFFFFFFFull);
            float4 b = loc4[o];
            chBox[r] = b;
            chArea[r] = area_of(b.x, b.y, b.z, b.w);
        }
        __syncthreads();

        // init dead[] vs all kept so far (no-op for first chunk)
        for (int q = tid; q < M; q += NT) {
            bool dd = false;
            if (kt0 > 0) {
                float4 cb = chBox[q]; float ca = chArea[q];
                for (int k2 = 0; k2 < kt0 && !dd; ++k2) {
                    float4 kb = keptBox[k2];
                    dd = iou_gt_thr(kb.x, kb.y, kb.z, kb.w, keptArea[k2],
                                    cb.x, cb.y, cb.z, cb.w, ca);
                }
            }
            dead[q] = dd ? 1 : 0;
        }
        __syncthreads();

        // ---- greedy rounds over sorted chunk, 256 positions per round ----
        for (int p0 = 0; p0 < M; p0 += BATCH) {
            if (ctrl[CT_KT] >= MAXDET) break;       // uniform (barrier-synced LDS read)
            int B = M - p0; if (B > BATCH) B = BATCH;
            for (int t = tid; t < BATCH * 8; t += NT) matT[t] = 0u;
            __syncthreads();
            // transposed pairwise suppression matrix (row j, bits over i<j); skip dead
            for (int p = tid; p < BATCH * BATCH; p += NT) {
                int i = p >> 8, j = p & (BATCH - 1);
                if (i < j && j < B && !dead[p0 + i] && !dead[p0 + j]) {
                    float4 bi = chBox[p0 + i], bj = chBox[p0 + j];
                    if (iou_gt_thr(bi.x, bi.y, bi.z, bi.w, chArea[p0 + i],
                                   bj.x, bj.y, bj.z, bj.w, chArea[p0 + j]))
                        atomicOr(&matT[(j << 3) + (i >> 5)], 1u << (i & 31));
                }
            }
            __syncthreads();
            // ---- parallel greedy fixpoint on wave 0 (register-resident columns) ----
            if (tid < 64) {
                const int L = tid;
                int ktBase = ctrl[CT_KT];
                u64 col[4][4];
                u32 am = 0;                      // alive bits of my 4 members (bit g)
                #pragma unroll
                for (int g = 0; g < 4; ++g) {
                    int m = g * 64 + L;
                    #pragma unroll
                    for (int w = 0; w < 4; ++w)
                        col[g][w] = ((u64)matT[(m << 3) + 2 * w + 1] << 32) | matT[(m << 3) + 2 * w];
                    if (m < B && !dead[p0 + m]) am |= 1u << g;
                }
                u32 cm = 0;                      // confirmed-kept bits
                for (int round = 0; round < BATCH; ++round) {
                    u64 aliveW[4];
                    #pragma unroll
                    for (int g = 0; g < 4; ++g) aliveW[g] = __ballot((am >> g) & 1u);
                    if (__ballot((am & ~cm) != 0u) == 0ull) break;   // all alive confirmed
                    u32 km = 0;
                    #pragma unroll
                    for (int g = 0; g < 4; ++g) {
                        u64 pnd = (col[g][0] & aliveW[0]) | (col[g][1] & aliveW[1]) |
                                  (col[g][2] & aliveW[2]) | (col[g][3] & aliveW[3]);
                        if (((am >> g) & 1u) && !((cm >> g) & 1u) && pnd == 0ull) km |= 1u << g;
                    }
                    u64 kW[4];
                    #pragma unroll
                    for (int g = 0; g < 4; ++g) kW[g] = __ballot((km >> g) & 1u);
                    cm |= km;
                    #pragma unroll
                    for (int g = 0; g < 4; ++g) {
                        u64 s = (col[g][0] & kW[0]) | (col[g][1] & kW[1]) |
                                (col[g][2] & kW[2]) | (col[g][3] & kW[3]);
                        if (s != 0ull) am &= ~(1u << g);   // suppressed by a confirmed keep
                    }
                }
                // collect kept (cm) in position order; truncate at the 512 cap
                u64 confW[4];
                #pragma unroll
                for (int g = 0; g < 4; ++g) confW[g] = __ballot((cm >> g) & 1u);
                int t0 = __popcll(confW[0]), t1 = __popcll(confW[1]), t2 = __popcll(confW[2]);
                #pragma unroll
                for (int g = 0; g < 4; ++g) {
                    if ((cm >> g) & 1u) {
                        int rank = __popcll(confW[g] & ((1ull << L) - 1ull));
                        if (g > 0) rank += t0;
                        if (g > 1) rank += t1;
                        if (g > 2) rank += t2;
                        int m = g * 64 + L;
                        keptB[rank] = m;
                        if (ktBase + rank < MAXDET) {
                            int pos = p0 + m;
                            u64 kk = key[pos];
                            keptIdx[ktBase + rank] = (int)(u32)(kk & 0xFFFFFFFFull);
                            keptSB[ktBase + rank] = ~(u32)(kk >> 32);
                            keptBox[ktBase + rank] = chBox[pos];
                            keptArea[ktBase + rank] = chArea[pos];
                        }
                    }
                }
                if (L == 0) {
                    int tot = t0 + t1 + t2 + __popcll(confW[3]);
                    int nk = tot; if (ktBase + nk > MAXDET) nk = MAXDET - ktBase;
                    ctrl[CT_KT] = ktBase + nk;
                    ctrl[CT_NN] = tot;
                }
            }
            __syncthreads();
            // sweep: new kept vs remaining chunk positions (skipped once capped)
            int nn = ctrl[CT_NN];
            if (ctrl[CT_KT] < MAXDET && nn > 0) {
                for (int q = p0 + B + tid; q < M; q += NT) {
                    if (dead[q]) continue;
                    float4 cb = chBox[q]; float ca = chArea[q];
                    bool dd = false;
                    for (int n = 0; n < nn && !dd; ++n) {
                        int bi = p0 + keptB[n];
                        float4 kb = chBox[bi];
                        dd = iou_gt_thr(kb.x, kb.y, kb.z, kb.w, chArea[bi],
                                        cb.x, cb.y, cb.z, cb.w, ca);
                    }
                    if (dd) dead[q] = 1;
                }
            }
            __syncthreads();
        }
        bhi = blo;
    }

    // ---- outputs: boxes[512*4] | landms[512*10] | scores[512] ----
    __syncthreads();
    int kt = ctrl[CT_KT];
    if (tid < MAXDET) {
        int k = tid;
        if (k < kt) {
            int o = keptIdx[k];
            float4 b = keptBox[k];
            *(float4*)(out + 4 * k) = b;
            #pragma unroll
            for (int j = 0; j < 10; ++j) out[2048 + 10 * k + j] = landms[10 * o + j];
            out[7168 + k] = __uint_as_float(keptSB[k]);
        } else {
            *(float4*)(out + 4 * k) = make_float4(0.f, 0.f, 0.f, 0.f);
            #pragma unroll
            for (int j = 0; j < 10; ++j) out[2048 + 10 * k + j] = 0.0f;
            out[7168 + k] = 0.0f;
        }
    }
}

extern "C" void kernel_launch(void* const* d_in, const int* in_sizes, int n_in,
                              void* d_out, int out_size, void* d_ws, size_t ws_size,
                              hipStream_t stream) {
    const float* loc    = (const float*)d_in[0];   // [43008,4]
    const float* conf   = (const float*)d_in[1];   // [43008,2]
    const float* landms = (const float*)d_in[2];   // [43008,10]
    float* out = (float*)d_out;                    // 7680 floats

    char* ws = (char*)d_ws;
    u32* histG = (u32*)(ws + 0);          // 4 KB
    u32* sufG  = (u32*)(ws + 4096);       // 4 KB
    u32* curG  = (u32*)(ws + 8192);       // 4 KB
    u64* wsKey = (u64*)(ws + 12288);      // 344064 B

    hipMemsetAsync(histG, 0, NBIN * sizeof(u32), stream);
    hist_k<<<N_BOX / 256, 256, 0, stream>>>(conf, histG);
    scan_k<<<1, 1024, 0, stream>>>(histG, sufG, curG);
    scatter_k<<<N_BOX / 256, 256, 0, stream>>>(conf, curG, wsKey);
    nms_k<<<1, NT, 0, stream>>>(sufG, wsKey, loc, landms, out);
}

// Round 12
// 147.102 us; speedup vs baseline: 21.7616x; 2.1961x over previous
//
#include <hip/hip_runtime.h>

#define N_BOX   43008
#define MAXDET  512
#define NBIN    1024
#define NMS_THR 0.4f

typedef unsigned long long u64;
typedef unsigned int u32;

// ---------- exact-arithmetic helpers (match numpy f32, no FMA contraction) ----------
__device__ __forceinline__ float area_of(float x1, float y1, float x2, float y2) {
    return __fmul_rn(__fsub_rn(x2, x1), __fsub_rn(y2, y1));
}

// add/fmax/fmin are bitwise-commutative, so operand roles cannot change the decision
__device__ __forceinline__ bool iou_gt_thr(float ax1, float ay1, float ax2, float ay2, float aar,
                                           float bx1, float by1, float bx2, float by2, float bar) {
    float xx1 = fmaxf(ax1, bx1);
    float yy1 = fmaxf(ay1, by1);
    float xx2 = fminf(ax2, bx2);
    float yy2 = fminf(ay2, by2);
    float dx = __fsub_rn(xx2, xx1);
    float dy = __fsub_rn(yy2, yy1);
    if (dx <= 0.0f || dy <= 0.0f) return false;   // inter == 0 -> iou == 0, not > 0.4
    float inter = __fmul_rn(dx, dy);
    float denom = __fsub_rn(__fadd_rn(aar, bar), inter);  // areas[i] + areas[j] - inter
    return inter / denom > NMS_THR;               // IEEE f32 division (no fast-math)
}

// monotone score -> bin (s1 >= s2 => bin1 >= bin2); equal scores share a bin
__device__ __forceinline__ int bin_of(float s) {
    int b = (int)(s * 1024.0f);
    return b < 0 ? 0 : (b > 1023 ? 1023 : b);
}

// ---------- k1: global histogram of score bins ----------
__global__ void hist_k(const float* __restrict__ conf, u32* __restrict__ histG) {
    int i = blockIdx.x * 256 + threadIdx.x;
    if (i < N_BOX) atomicAdd(&histG[bin_of(conf[2 * i + 1])], 1u);
}

// ---------- k2: suffix scan + descending-bin scatter cursors ----------
__global__ __launch_bounds__(1024) void scan_k(const u32* __restrict__ histG,
                                               u32* __restrict__ sufG,
                                               u32* __restrict__ curG) {
    __shared__ u32 a[NBIN];
    int t = threadIdx.x;
    a[t] = histG[t];
    __syncthreads();
    for (int d = 1; d < NBIN; d <<= 1) {
        u32 v = (t + d < NBIN) ? a[t + d] : 0u;
        __syncthreads();
        a[t] += v;
        __syncthreads();
    }
    sufG[t] = a[t];                               // suf[b] = count of bins >= b; bin b segment = [suf[b+1], suf[b])
    curG[t] = (t + 1 >= NBIN) ? 0u : a[t + 1];
}

// ---------- k3: counting-sort scatter of keys into bin segments ----------
__global__ void scatter_k(const float* __restrict__ conf, u32* __restrict__ curG,
                          u64* __restrict__ wsKey) {
    int i = blockIdx.x * 256 + threadIdx.x;
    if (i >= N_BOX) return;
    float s = conf[2 * i + 1];
    u32 slot = atomicAdd(&curG[bin_of(s)], 1u);
    u32 sb = __float_as_uint(s);                  // scores >= 0: bit order == float order
    wsKey[slot] = ((u64)(~sb) << 32) | (u32)i;
}

// ---------- k4: exact rank-sort of the top-MCAP region (parallel, per-bin segments) ----------
__global__ void sort_k(const u32* __restrict__ sufG, const u64* __restrict__ wsKey,
                       const float* __restrict__ loc, u64* __restrict__ wsSortKey,
                       float4* __restrict__ wsBoxS, float* __restrict__ wsAreaS, int MCAP) {
    int r = blockIdx.x * 256 + threadIdx.x;
    if (r >= N_BOX) return;
    u64 k = wsKey[r];
    u32 sb = ~(u32)(k >> 32);
    int b = bin_of(__uint_as_float(sb));
    int s0 = (b + 1 >= NBIN) ? 0 : (int)sufG[b + 1];
    if (s0 >= MCAP) return;                       // whole segment beyond sorted region
    int e0 = (int)sufG[b];
    int rank = s0;
    for (int q = s0; q < e0; ++q) rank += (wsKey[q] < k) ? 1 : 0;   // keys unique (idx in low bits)
    if (rank < MCAP) {
        wsSortKey[rank] = k;
        int o = (int)(u32)(k & 0xFFFFFFFFull);
        float4 bx = ((const float4*)loc)[o];
        wsBoxS[rank] = bx;
        wsAreaS[rank] = area_of(bx.x, bx.y, bx.z, bx.w);
    }
}

// ---------- k5: parallel suppression bit-matrix over lower triangle, 256x256 tiles ----------
// row j (bits i<j): wsMat[j*W32 + w] — tile (ti,tj) owns words [ti*8, ti*8+8) of rows in tile tj.
__global__ __launch_bounds__(256) void mat_k(const float4* __restrict__ wsBoxS,
                                             const float* __restrict__ wsAreaS,
                                             u32* __restrict__ wsMat, int MCAP) {
    int l = blockIdx.x;
    int tj = (int)((sqrtf(8.0f * (float)l + 1.0f) - 1.0f) * 0.5f);
    while ((tj + 1) * (tj + 2) / 2 <= l) ++tj;
    while (tj * (tj + 1) / 2 > l) --tj;
    int ti = l - tj * (tj + 1) / 2;

    __shared__ float4 bI[256];
    __shared__ float  aI[256];
    const int t = threadIdx.x;
    const int gi0 = ti * 256;
    bI[t] = wsBoxS[gi0 + t];
    aI[t] = wsAreaS[gi0 + t];
    __syncthreads();

    const int gj = tj * 256 + t;
    float4 bj = wsBoxS[gj];
    float  aj = wsAreaS[gj];
    const int W32 = MCAP >> 5;
    size_t rowBase = (size_t)gj * W32 + ti * 8;
    #pragma unroll
    for (int w = 0; w < 8; ++w) {
        u32 bits = 0u;
        for (int i2 = 0; i2 < 32; ++i2) {
            int i = w * 32 + i2;
            int gi = gi0 + i;
            if (gi < gj) {
                float4 bi = bI[i];
                if (iou_gt_thr(bi.x, bi.y, bi.z, bi.w, aI[i],
                               bj.x, bj.y, bj.z, bj.w, aj))
                    bits |= 1u << i2;
            }
        }
        wsMat[rowBase + w] = bits;
    }
}

// ---------- k6: sequential greedy scan — zero IoU, pure bit ops (single WG) ----------
__global__ __launch_bounds__(1024, 1) void nms2_k(const u64* __restrict__ wsSortKey,
                                                  const u32* __restrict__ wsMat,
                                                  const float* __restrict__ loc,
                                                  const float* __restrict__ landms,
                                                  float* __restrict__ out, int MCAP) {
    const float4* loc4 = (const float4*)loc;
    __shared__ u32 keptMask[256];        // bits over positions [0, MCAP), MCAP <= 8192
    __shared__ u32 matT[256 * 8];        // in-batch rows: row m = 256 suppressor bits
    __shared__ u32 deadF[8];             // dead-from-prior bits over 256 members
    __shared__ int keptIdx[MAXDET];
    __shared__ u32 keptSB[MAXDET];
    __shared__ int ctrl[4];              // 0 = keptTotal

    const int tid = threadIdx.x;
    const int W32 = MCAP >> 5;
    for (int w = tid; w < W32; w += 1024) keptMask[w] = 0u;
    if (tid == 0) ctrl[0] = 0;
    __syncthreads();

    for (int p0 = 0; p0 < MCAP; p0 += 256) {
        if (ctrl[0] >= MAXDET) break;               // uniform (post-barrier LDS read)
        // ---- phase A: stage in-batch matrix words; zero deadF ----
        {
            int u = tid;
            #pragma unroll
            for (int rr = 0; rr < 2; ++rr, u += 1024) {
                int m = u >> 3, w = u & 7;
                matT[u] = wsMat[(size_t)(p0 + m) * W32 + (p0 >> 5) + w];
            }
        }
        if (tid < 8) deadF[tid] = 0u;
        __syncthreads();
        // ---- phase B: prefix-AND against keptMask -> dead-from-prior ----
        int WP = p0 >> 5;
        if (WP > 0) {
            int W = 256 * WP;
            for (int u = tid; u < W; u += 1024) {
                int m = u / WP, w = u - m * WP;
                if (wsMat[(size_t)(p0 + m) * W32 + w] & keptMask[w])
                    atomicOr(&deadF[m >> 5], 1u << (m & 31));
            }
        }
        __syncthreads();
        // ---- phase C: greedy fixpoint on wave 0 (register-resident columns) ----
        if (tid < 64) {
            const int L = tid;
            int ktBase = ctrl[0];
            u64 col[4][4];
            u32 am = 0;
            #pragma unroll
            for (int g = 0; g < 4; ++g) {
                int m = g * 64 + L;
                #pragma unroll
                for (int w = 0; w < 4; ++w)
                    col[g][w] = ((u64)matT[(m << 3) + 2 * w + 1] << 32) | matT[(m << 3) + 2 * w];
                if (!((deadF[m >> 5] >> (m & 31)) & 1u)) am |= 1u << g;
            }
            u32 cm = 0;
            for (int round = 0; round < 256; ++round) {
                u64 aliveW[4];
                #pragma unroll
                for (int g = 0; g < 4; ++g) aliveW[g] = __ballot((am >> g) & 1u);
                if (__ballot((am & ~cm) != 0u) == 0ull) break;
                u32 km = 0;
                #pragma unroll
                for (int g = 0; g < 4; ++g) {
                    u64 pnd = (col[g][0] & aliveW[0]) | (col[g][1] & aliveW[1]) |
                              (col[g][2] & aliveW[2]) | (col[g][3] & aliveW[3]);
                    if (((am >> g) & 1u) && !((cm >> g) & 1u) && pnd == 0ull) km |= 1u << g;
                }
                u64 kW[4];
                #pragma unroll
                for (int g = 0; g < 4; ++g) kW[g] = __ballot((km >> g) & 1u);
                cm |= km;
                #pragma unroll
                for (int g = 0; g < 4; ++g) {
                    u64 s = (col[g][0] & kW[0]) | (col[g][1] & kW[1]) |
                            (col[g][2] & kW[2]) | (col[g][3] & kW[3]);
                    if (s != 0ull) am &= ~(1u << g);
                }
            }
            // collect confirmed in position order; truncate at the 512 cap
            u64 confW[4];
            #pragma unroll
            for (int g = 0; g < 4; ++g) confW[g] = __ballot((cm >> g) & 1u);
            int t0 = __popcll(confW[0]), t1 = __popcll(confW[1]), t2 = __popcll(confW[2]);
            #pragma unroll
            for (int g = 0; g < 4; ++g) {
                if ((cm >> g) & 1u) {
                    int rank = __popcll(confW[g] & ((1ull << L) - 1ull));
                    if (g > 0) rank += t0;
                    if (g > 1) rank += t1;
                    if (g > 2) rank += t2;
                    int m = g * 64 + L;
                    int pos = p0 + m;
                    atomicOr(&keptMask[pos >> 5], 1u << (pos & 31));
                    if (ktBase + rank < MAXDET) {
                        u64 kk = wsSortKey[pos];
                        keptIdx[ktBase + rank] = (int)(u32)(kk & 0xFFFFFFFFull);
                        keptSB[ktBase + rank] = ~(u32)(kk >> 32);
                    }
                }
            }
            if (L == 0) {
                int tot = t0 + t1 + t2 + __popcll(confW[3]);
                int nk = tot; if (ktBase + nk > MAXDET) nk = MAXDET - ktBase;
                ctrl[0] = ktBase + nk;
            }
        }
        __syncthreads();
    }

    // ---- outputs: boxes[512*4] | landms[512*10] | scores[512] ----
    __syncthreads();
    int kt = ctrl[0];
    if (tid < MAXDET) {
        int k = tid;
        if (k < kt) {
            int o = keptIdx[k];
            float4 b = loc4[o];
            *(float4*)(out + 4 * k) = b;
            #pragma unroll
            for (int j = 0; j < 10; ++j) out[2048 + 10 * k + j] = landms[10 * o + j];
            out[7168 + k] = __uint_as_float(keptSB[k]);
        } else {
            *(float4*)(out + 4 * k) = make_float4(0.f, 0.f, 0.f, 0.f);
            #pragma unroll
            for (int j = 0; j < 10; ++j) out[2048 + 10 * k + j] = 0.0f;
            out[7168 + k] = 0.0f;
        }
    }
}

extern "C" void kernel_launch(void* const* d_in, const int* in_sizes, int n_in,
                              void* d_out, int out_size, void* d_ws, size_t ws_size,
                              hipStream_t stream) {
    const float* loc    = (const float*)d_in[0];   // [43008,4]
    const float* conf   = (const float*)d_in[1];   // [43008,2]
    const float* landms = (const float*)d_in[2];   // [43008,10]
    float* out = (float*)d_out;                    // 7680 floats

    // pick largest matrix region that fits ws (scan depth here ~550; 4096 = 7x margin)
    const size_t fixed = 12288 + (size_t)N_BOX * 8;       // hist+suf+cur + wsKey
    int MCAP = 1024;
    const int cands[3] = {4096, 2048, 1024};
    for (int c = 0; c < 3; ++c) {
        int m = cands[c];
        size_t need = fixed + (size_t)m * (8 + 16 + 4) + (size_t)m * ((size_t)m / 8);
        if (ws_size >= need) { MCAP = m; break; }
    }

    char* ws = (char*)d_ws;
    u32*    histG     = (u32*)(ws + 0);
    u32*    sufG      = (u32*)(ws + 4096);
    u32*    curG      = (u32*)(ws + 8192);
    u64*    wsKey     = (u64*)(ws + 12288);
    char*   p         = ws + fixed;
    u64*    wsSortKey = (u64*)p;            p += (size_t)MCAP * 8;
    float4* wsBoxS    = (float4*)p;         p += (size_t)MCAP * 16;
    float*  wsAreaS   = (float*)p;          p += (size_t)MCAP * 4;
    u32*    wsMat     = (u32*)p;

    int T = MCAP / 256;
    hipMemsetAsync(histG, 0, NBIN * sizeof(u32), stream);
    hist_k<<<N_BOX / 256, 256, 0, stream>>>(conf, histG);
    scan_k<<<1, 1024, 0, stream>>>(histG, sufG, curG);
    scatter_k<<<N_BOX / 256, 256, 0, stream>>>(conf, curG, wsKey);
    sort_k<<<N_BOX / 256, 256, 0, stream>>>(sufG, wsKey, loc, wsSortKey, wsBoxS, wsAreaS, MCAP);
    mat_k<<<T * (T + 1) / 2, 256, 0, stream>>>(wsBoxS, wsAreaS, wsMat, MCAP);
    nms2_k<<<1, 1024, 0, stream>>>(wsSortKey, wsMat, loc, landms, out, MCAP);
}

// Round 16
// 117.733 us; speedup vs baseline: 27.1900x; 1.2494x over previous
//
#include <hip/hip_runtime.h>

#define N_BOX   43008
#define MAXDET  512
#define NBIN    1024
#define NMS_THR 0.4f

typedef unsigned long long u64;
typedef unsigned int u32;

// ---------- exact-arithmetic helpers (match numpy f32, no FMA contraction) ----------
__device__ __forceinline__ float area_of(float x1, float y1, float x2, float y2) {
    return __fmul_rn(__fsub_rn(x2, x1), __fsub_rn(y2, y1));
}

// add/fmax/fmin are bitwise-commutative, so operand roles cannot change the decision
__device__ __forceinline__ bool iou_gt_thr(float ax1, float ay1, float ax2, float ay2, float aar,
                                           float bx1, float by1, float bx2, float by2, float bar) {
    float xx1 = fmaxf(ax1, bx1);
    float yy1 = fmaxf(ay1, by1);
    float xx2 = fminf(ax2, bx2);
    float yy2 = fminf(ay2, by2);
    float dx = __fsub_rn(xx2, xx1);
    float dy = __fsub_rn(yy2, yy1);
    if (dx <= 0.0f || dy <= 0.0f) return false;   // inter == 0 -> iou == 0, not > 0.4
    float inter = __fmul_rn(dx, dy);
    float denom = __fsub_rn(__fadd_rn(aar, bar), inter);  // areas[i] + areas[j] - inter
    return inter / denom > NMS_THR;               // IEEE f32 division (no fast-math)
}

// monotone score -> bin (s1 >= s2 => bin1 >= bin2); equal scores share a bin
__device__ __forceinline__ int bin_of(float s) {
    int b = (int)(s * 1024.0f);
    return b < 0 ? 0 : (b > 1023 ? 1023 : b);
}

// ---------- k1: global histogram of score bins ----------
__global__ void hist_k(const float* __restrict__ conf, u32* __restrict__ histG) {
    int i = blockIdx.x * 256 + threadIdx.x;
    if (i < N_BOX) atomicAdd(&histG[bin_of(conf[2 * i + 1])], 1u);
}

// ---------- k2: suffix scan + descending-bin scatter cursors ----------
__global__ __launch_bounds__(1024) void scan_k(const u32* __restrict__ histG,
                                               u32* __restrict__ sufG,
                                               u32* __restrict__ curG) {
    __shared__ u32 a[NBIN];
    int t = threadIdx.x;
    a[t] = histG[t];
    __syncthreads();
    for (int d = 1; d < NBIN; d <<= 1) {
        u32 v = (t + d < NBIN) ? a[t + d] : 0u;
        __syncthreads();
        a[t] += v;
        __syncthreads();
    }
    sufG[t] = a[t];                               // suf[b] = count of bins >= b; bin b segment = [suf[b+1], suf[b])
    curG[t] = (t + 1 >= NBIN) ? 0u : a[t + 1];
}

// ---------- k3: counting-sort scatter of keys into bin segments ----------
__global__ void scatter_k(const float* __restrict__ conf, u32* __restrict__ curG,
                          u64* __restrict__ wsKey) {
    int i = blockIdx.x * 256 + threadIdx.x;
    if (i >= N_BOX) return;
    float s = conf[2 * i + 1];
    u32 slot = atomicAdd(&curG[bin_of(s)], 1u);
    u32 sb = __float_as_uint(s);                  // scores >= 0: bit order == float order
    wsKey[slot] = ((u64)(~sb) << 32) | (u32)i;
}

// ---------- k4: exact rank-sort of the top-MCAP region (parallel, per-bin segments) ----------
__global__ void sort_k(const u32* __restrict__ sufG, const u64* __restrict__ wsKey,
                       const float* __restrict__ loc, u64* __restrict__ wsSortKey,
                       float4* __restrict__ wsBoxS, float* __restrict__ wsAreaS, int MCAP) {
    int r = blockIdx.x * 256 + threadIdx.x;
    if (r >= N_BOX) return;
    u64 k = wsKey[r];
    u32 sb = ~(u32)(k >> 32);
    int b = bin_of(__uint_as_float(sb));
    int s0 = (b + 1 >= NBIN) ? 0 : (int)sufG[b + 1];
    if (s0 >= MCAP) return;                       // whole segment beyond sorted region
    int e0 = (int)sufG[b];
    int rank = s0;
    for (int q = s0; q < e0; ++q) rank += (wsKey[q] < k) ? 1 : 0;   // keys unique (idx in low bits)
    if (rank < MCAP) {
        wsSortKey[rank] = k;
        int o = (int)(u32)(k & 0xFFFFFFFFull);
        float4 bx = ((const float4*)loc)[o];
        wsBoxS[rank] = bx;
        wsAreaS[rank] = area_of(bx.x, bx.y, bx.z, bx.w);
    }
}

// ---------- k5: parallel suppression bit-matrix, register-blocked 4j x 32i per thread ----------
// row j (bits i<j): wsMat[j*W32 + w] — tile (ti,tj): 512 threads, thread (jq,iw) owns
// rows tj*256+jq*4 .. +3, word ti*8+iw. Single writer per word; 4-way ILP per LDS read.
__global__ __launch_bounds__(512) void mat_k(const float4* __restrict__ wsBoxS,
                                             const float* __restrict__ wsAreaS,
                                             u32* __restrict__ wsMat, int MCAP) {
    int l = blockIdx.x;
    int tj = (int)((sqrtf(8.0f * (float)l + 1.0f) - 1.0f) * 0.5f);
    while ((tj + 1) * (tj + 2) / 2 <= l) ++tj;
    while (tj * (tj + 1) / 2 > l) --tj;
    int ti = l - tj * (tj + 1) / 2;

    __shared__ float4 bI[256];
    __shared__ float  aI[256];
    const int t = threadIdx.x;
    const int gi0 = ti * 256;
    if (t < 256) {
        bI[t] = wsBoxS[gi0 + t];
        aI[t] = wsAreaS[gi0 + t];
    }
    __syncthreads();

    const int jq = t & 63;          // 64 j-quads -> 256 j rows
    const int iw = t >> 6;          // 8 words -> 256 i cols
    const int j0 = tj * 256 + jq * 4;
    float4 b0 = wsBoxS[j0 + 0], b1 = wsBoxS[j0 + 1], b2 = wsBoxS[j0 + 2], b3 = wsBoxS[j0 + 3];
    float  a0 = wsAreaS[j0 + 0], a1 = wsAreaS[j0 + 1], a2 = wsAreaS[j0 + 2], a3 = wsAreaS[j0 + 3];

    u32 w0 = 0u, w1 = 0u, w2 = 0u, w3 = 0u;
    const int ib = iw * 32;
    #pragma unroll 4
    for (int i2 = 0; i2 < 32; ++i2) {
        int i = ib + i2;
        int gi = gi0 + i;
        float4 bi = bI[i];
        float  ai = aI[i];
        if (gi < j0 + 0 && iou_gt_thr(bi.x, bi.y, bi.z, bi.w, ai, b0.x, b0.y, b0.z, b0.w, a0)) w0 |= 1u << i2;
        if (gi < j0 + 1 && iou_gt_thr(bi.x, bi.y, bi.z, bi.w, ai, b1.x, b1.y, b1.z, b1.w, a1)) w1 |= 1u << i2;
        if (gi < j0 + 2 && iou_gt_thr(bi.x, bi.y, bi.z, bi.w, ai, b2.x, b2.y, b2.z, b2.w, a2)) w2 |= 1u << i2;
        if (gi < j0 + 3 && iou_gt_thr(bi.x, bi.y, bi.z, bi.w, ai, b3.x, b3.y, b3.z, b3.w, a3)) w3 |= 1u << i2;
    }
    const int W32 = MCAP >> 5;
    const int wcol = ti * 8 + iw;
    wsMat[(size_t)(j0 + 0) * W32 + wcol] = w0;
    wsMat[(size_t)(j0 + 1) * W32 + wcol] = w1;
    wsMat[(size_t)(j0 + 2) * W32 + wcol] = w2;
    wsMat[(size_t)(j0 + 3) * W32 + wcol] = w3;
}

// ---------- k6: sequential greedy scan — zero IoU, pure bit ops (single WG) ----------
__global__ __launch_bounds__(1024, 1) void nms2_k(const u64* __restrict__ wsSortKey,
                                                  const u32* __restrict__ wsMat,
                                                  const float* __restrict__ loc,
                                                  const float* __restrict__ landms,
                                                  float* __restrict__ out, int MCAP) {
    const float4* loc4 = (const float4*)loc;
    __shared__ u32 keptMask[256];        // bits over positions [0, MCAP), MCAP <= 8192
    __shared__ u32 matT[256 * 8];        // in-batch rows: row m = 256 suppressor bits
    __shared__ u32 deadF[8];             // dead-from-prior bits over 256 members
    __shared__ int keptIdx[MAXDET];
    __shared__ u32 keptSB[MAXDET];
    __shared__ int ctrl[4];              // 0 = keptTotal

    const int tid = threadIdx.x;
    const int W32 = MCAP >> 5;
    for (int w = tid; w < W32; w += 1024) keptMask[w] = 0u;
    if (tid == 0) ctrl[0] = 0;
    __syncthreads();

    for (int p0 = 0; p0 < MCAP; p0 += 256) {
        if (ctrl[0] >= MAXDET) break;               // uniform (post-barrier LDS read)
        // ---- phase A: stage in-batch matrix words; zero deadF ----
        {
            int u = tid;
            #pragma unroll
            for (int rr = 0; rr < 2; ++rr, u += 1024) {
                int m = u >> 3, w = u & 7;
                matT[u] = wsMat[(size_t)(p0 + m) * W32 + (p0 >> 5) + w];
            }
        }
        if (tid < 8) deadF[tid] = 0u;
        __syncthreads();
        // ---- phase B: prefix-AND against keptMask -> dead-from-prior ----
        int WP = p0 >> 5;
        if (WP > 0) {
            int W = 256 * WP;
            for (int u = tid; u < W; u += 1024) {
                int m = u / WP, w = u - m * WP;
                if (wsMat[(size_t)(p0 + m) * W32 + w] & keptMask[w])
                    atomicOr(&deadF[m >> 5], 1u << (m & 31));
            }
        }
        __syncthreads();
        // ---- phase C: greedy fixpoint on wave 0 (register-resident columns) ----
        if (tid < 64) {
            const int L = tid;
            int ktBase = ctrl[0];
            u64 col[4][4];
            u32 am = 0;
            #pragma unroll
            for (int g = 0; g < 4; ++g) {
                int m = g * 64 + L;
                #pragma unroll
                for (int w = 0; w < 4; ++w)
                    col[g][w] = ((u64)matT[(m << 3) + 2 * w + 1] << 32) | matT[(m << 3) + 2 * w];
                if (!((deadF[m >> 5] >> (m & 31)) & 1u)) am |= 1u << g;
            }
            u32 cm = 0;
            for (int round = 0; round < 256; ++round) {
                u64 aliveW[4];
                #pragma unroll
                for (int g = 0; g < 4; ++g) aliveW[g] = __ballot((am >> g) & 1u);
                if (__ballot((am & ~cm) != 0u) == 0ull) break;
                u32 km = 0;
                #pragma unroll
                for (int g = 0; g < 4; ++g) {
                    u64 pnd = (col[g][0] & aliveW[0]) | (col[g][1] & aliveW[1]) |
                              (col[g][2] & aliveW[2]) | (col[g][3] & aliveW[3]);
                    if (((am >> g) & 1u) && !((cm >> g) & 1u) && pnd == 0ull) km |= 1u << g;
                }
                u64 kW[4];
                #pragma unroll
                for (int g = 0; g < 4; ++g) kW[g] = __ballot((km >> g) & 1u);
                cm |= km;
                #pragma unroll
                for (int g = 0; g < 4; ++g) {
                    u64 s = (col[g][0] & kW[0]) | (col[g][1] & kW[1]) |
                            (col[g][2] & kW[2]) | (col[g][3] & kW[3]);
                    if (s != 0ull) am &= ~(1u << g);
                }
            }
            // collect confirmed in position order; truncate at the 512 cap
            u64 confW[4];
            #pragma unroll
            for (int g = 0; g < 4; ++g) confW[g] = __ballot((cm >> g) & 1u);
            int t0 = __popcll(confW[0]), t1 = __popcll(confW[1]), t2 = __popcll(confW[2]);
            #pragma unroll
            for (int g = 0; g < 4; ++g) {
                if ((cm >> g) & 1u) {
                    int rank = __popcll(confW[g] & ((1ull << L) - 1ull));
                    if (g > 0) rank += t0;
                    if (g > 1) rank += t1;
                    if (g > 2) rank += t2;
                    int m = g * 64 + L;
                    int pos = p0 + m;
                    atomicOr(&keptMask[pos >> 5], 1u << (pos & 31));
                    if (ktBase + rank < MAXDET) {
                        u64 kk = wsSortKey[pos];
                        keptIdx[ktBase + rank] = (int)(u32)(kk & 0xFFFFFFFFull);
                        keptSB[ktBase + rank] = ~(u32)(kk >> 32);
                    }
                }
            }
            if (L == 0) {
                int tot = t0 + t1 + t2 + __popcll(confW[3]);
                int nk = tot; if (ktBase + nk > MAXDET) nk = MAXDET - ktBase;
                ctrl[0] = ktBase + nk;
            }
        }
        __syncthreads();
    }

    // ---- outputs: boxes[512*4] | landms[512*10] | scores[512] ----
    __syncthreads();
    int kt = ctrl[0];
    if (tid < MAXDET) {
        int k = tid;
        if (k < kt) {
            int o = keptIdx[k];
            float4 b = loc4[o];
            *(float4*)(out + 4 * k) = b;
            #pragma unroll
            for (int j = 0; j < 10; ++j) out[2048 + 10 * k + j] = landms[10 * o + j];
            out[7168 + k] = __uint_as_float(keptSB[k]);
        } else {
            *(float4*)(out + 4 * k) = make_float4(0.f, 0.f, 0.f, 0.f);
            #pragma unroll
            for (int j = 0; j < 10; ++j) out[2048 + 10 * k + j] = 0.0f;
            out[7168 + k] = 0.0f;
        }
    }
}

extern "C" void kernel_launch(void* const* d_in, const int* in_sizes, int n_in,
                              void* d_out, int out_size, void* d_ws, size_t ws_size,
                              hipStream_t stream) {
    const float* loc    = (const float*)d_in[0];   // [43008,4]
    const float* conf   = (const float*)d_in[1];   // [43008,2]
    const float* landms = (const float*)d_in[2];   // [43008,10]
    float* out = (float*)d_out;                    // 7680 floats

    // pick largest matrix region that fits ws (scan depth here ~550; 4096 = 7x margin)
    const size_t fixed = 12288 + (size_t)N_BOX * 8;       // hist+suf+cur + wsKey
    int MCAP = 1024;
    const int cands[3] = {4096, 2048, 1024};
    for (int c = 0; c < 3; ++c) {
        int m = cands[c];
        size_t need = fixed + (size_t)m * (8 + 16 + 4) + (size_t)m * ((size_t)m / 8);
        if (ws_size >= need) { MCAP = m; break; }
    }

    char* ws = (char*)d_ws;
    u32*    histG     = (u32*)(ws + 0);
    u32*    sufG      = (u32*)(ws + 4096);
    u32*    curG      = (u32*)(ws + 8192);
    u64*    wsKey     = (u64*)(ws + 12288);
    char*   p         = ws + fixed;
    u64*    wsSortKey = (u64*)p;            p += (size_t)MCAP * 8;
    float4* wsBoxS    = (float4*)p;         p += (size_t)MCAP * 16;
    float*  wsAreaS   = (float*)p;          p += (size_t)MCAP * 4;
    u32*    wsMat     = (u32*)p;

    int T = MCAP / 256;
    hipMemsetAsync(histG, 0, NBIN * sizeof(u32), stream);
    hist_k<<<N_BOX / 256, 256, 0, stream>>>(conf, histG);
    scan_k<<<1, 1024, 0, stream>>>(histG, sufG, curG);
    scatter_k<<<N_BOX / 256, 256, 0, stream>>>(conf, curG, wsKey);
    sort_k<<<N_BOX / 256, 256, 0, stream>>>(sufG, wsKey, loc, wsSortKey, wsBoxS, wsAreaS, MCAP);
    mat_k<<<T * (T + 1) / 2, 512, 0, stream>>>(wsBoxS, wsAreaS, wsMat, MCAP);
    nms2_k<<<1, 1024, 0, stream>>>(wsSortKey, wsMat, loc, landms, out, MCAP);
}